// Round 16
// baseline (245.369 us; speedup 1.0000x reference)
//
#include <hip/hip_runtime.h>
#include <hip/hip_bf16.h>
#include <cstdint>

#define B_SZn 4
#define SEQ_L 4096
#define D_MODELn 512
#define D_INNERn 1024
#define N_HEADSn 16
#define HEAD_DIMn 64
#define D_STATEn 64
#define CHUNKn 64
#define NCHUNK (SEQ_L / CHUNKn)          // 64
#define BL (B_SZn * SEQ_L)               // 16384
#define XDBL_N (N_HEADSn + 2 * D_STATEn) // 144

typedef __hip_bfloat16 bf16;
typedef __bf16 bf16x8 __attribute__((ext_vector_type(8)));
typedef float f32x4 __attribute__((ext_vector_type(4)));

__device__ __forceinline__ float silu_f(float v) {
    return v / (1.0f + expf(-v));
}
__device__ __forceinline__ float b2f(unsigned short u) {
    return __uint_as_float((unsigned)u << 16);
}
__device__ __forceinline__ unsigned short f2b(float f) {
    bf16 h = __float2bfloat16(f);
    return *(unsigned short*)&h;
}
__device__ __forceinline__ void stf(float* p, float v) { *p = v; }
__device__ __forceinline__ void stf(bf16* p, float v) { *p = __float2bfloat16(v); }

__device__ __forceinline__ float4 us4_to_f4(ushort4 u) {
    float4 f;
    f.x = b2f(u.x); f.y = b2f(u.y); f.z = b2f(u.z); f.w = b2f(u.w);
    return f;
}

// async global->LDS 16B copy (m97/m193-proven pattern).
__device__ __forceinline__ void async_copy16(void* lds, const void* g) {
    __builtin_amdgcn_global_load_lds(
        (const __attribute__((address_space(1))) unsigned int*)g,
        (__attribute__((address_space(3))) unsigned int*)lds, 16, 0, 0);
}

// ---------------------------------------------------------------------------
// x (f32) -> bf16 elementwise convert
// ---------------------------------------------------------------------------
__global__ __launch_bounds__(256) void cvt_f32_bf16(
    const float* __restrict__ in, bf16* __restrict__ out) {
    const int idx = blockIdx.x * 256 + threadIdx.x;
    float4 v = *(const float4*)(in + (size_t)idx * 4);
    ushort4 o;
    o.x = f2b(v.x); o.y = f2b(v.y); o.z = f2b(v.z); o.w = f2b(v.w);
    *(ushort4*)((unsigned short*)out + (size_t)idx * 4) = o;
}

// ---------------------------------------------------------------------------
// Transpose + convert: out[c][r] = bf16(in[r][c]).  in [R][C] f32.
// ---------------------------------------------------------------------------
__global__ __launch_bounds__(256) void transpose_cvt(
    const float* __restrict__ in, bf16* __restrict__ out, int R, int C) {
    __shared__ float t[32][33];
    const int bc = blockIdx.x * 32, br = blockIdx.y * 32;
    const int tx = threadIdx.x & 31, ty = threadIdx.x >> 5;  // ty 0..7
#pragma unroll
    for (int i = ty; i < 32; i += 8) {
        int r = br + i, c = bc + tx;
        t[i][tx] = (r < R && c < C) ? in[(size_t)r * C + c] : 0.f;
    }
    __syncthreads();
#pragma unroll
    for (int i = ty; i < 32; i += 8) {
        int c = bc + i, r = br + tx;
        if (c < C && r < R) out[(size_t)c * R + r] = __float2bfloat16(t[tx][i]);
    }
}

// ---------------------------------------------------------------------------
// bf16 MFMA GEMM, counted-vmcnt pipeline (T4, m218 pattern): 128x128 tile,
// BK=32, 2 LDS buffers (32KB total — same occupancy as r12/r14).
// STAGE(next) -> s_waitcnt vmcnt(4) (NOT 0: next tile's 4 loads stay in
// flight) -> raw s_barrier -> MFMA -> raw s_barrier.  Last iter drains 0.
// XCD-aware swizzle (T1).  M mult 128, K mult 32; N bounds-checked on store.
// ---------------------------------------------------------------------------
template <typename TO>
__global__ __launch_bounds__(256) void gemm_mfma(
    const bf16* __restrict__ A, const bf16* __restrict__ Bt,
    TO* __restrict__ C, int M, int N, int K) {
    __shared__ __align__(16) unsigned short Al[2][128 * 32];
    __shared__ __align__(16) unsigned short Bl[2][128 * 32];
    const int tid = threadIdx.x;
    const int wave = tid >> 6, lane = tid & 63;
    const int wm = (wave >> 1) * 64, wn = (wave & 1) * 64;
    int lin = blockIdx.y * gridDim.x + blockIdx.x;
    const int nwg = gridDim.x * gridDim.y;
    if ((nwg & 7) == 0) lin = (lin & 7) * (nwg >> 3) + (lin >> 3);
    const int bm = (lin / gridDim.x) * 128, bn = (lin % gridDim.x) * 128;
    f32x4 acc[4][4];
#pragma unroll
    for (int m = 0; m < 4; ++m)
#pragma unroll
        for (int n = 0; n < 4; ++n) acc[m][n] = (f32x4)(0.f);

    const int lrow = lane & 15, lk8 = (lane >> 4) * 8;
    const int srow = tid >> 2, sc8 = (tid & 3) * 8;
    auto STAGE = [&](int buf, int k) {  // 4 global_load_lds per thread
        async_copy16((char*)&Al[buf][0] + (size_t)(wave * 64) * 16,
                     A + (size_t)(bm + srow) * K + k + sc8);
        async_copy16((char*)&Al[buf][0] + (size_t)(256 + wave * 64) * 16,
                     A + (size_t)(bm + 64 + srow) * K + k + sc8);
        async_copy16((char*)&Bl[buf][0] + (size_t)(wave * 64) * 16,
                     Bt + (size_t)(bn + srow) * K + k + sc8);
        async_copy16((char*)&Bl[buf][0] + (size_t)(256 + wave * 64) * 16,
                     Bt + (size_t)(bn + 64 + srow) * K + k + sc8);
    };
    STAGE(0, 0);
    int cur = 0;
    for (int k0 = 0; k0 < K; k0 += 32) {
        if (k0 + 32 < K) {
            STAGE(cur ^ 1, k0 + 32);   // 8 in flight; oldest 4 = tile cur
            asm volatile("s_waitcnt vmcnt(4)" ::: "memory");
        } else {
            asm volatile("s_waitcnt vmcnt(0)" ::: "memory");
        }
        __builtin_amdgcn_sched_barrier(0);
        __builtin_amdgcn_s_barrier();   // all waves: tile-cur resident
        bf16x8 af[4], bfr[4];
#pragma unroll
        for (int m = 0; m < 4; ++m)
            af[m] = *(const bf16x8*)(&Al[cur][(wm + m * 16 + lrow) * 32 + lk8]);
#pragma unroll
        for (int n = 0; n < 4; ++n)
            bfr[n] = *(const bf16x8*)(&Bl[cur][(wn + n * 16 + lrow) * 32 + lk8]);
#pragma unroll
        for (int m = 0; m < 4; ++m)
#pragma unroll
            for (int n = 0; n < 4; ++n)
                acc[m][n] = __builtin_amdgcn_mfma_f32_16x16x32_bf16(
                    af[m], bfr[n], acc[m][n], 0, 0, 0);
        __builtin_amdgcn_sched_barrier(0);
        __builtin_amdgcn_s_barrier();   // reads of buf[cur] done before restage
        cur ^= 1;
    }
#pragma unroll
    for (int m = 0; m < 4; ++m) {
#pragma unroll
        for (int n = 0; n < 4; ++n) {
#pragma unroll
            for (int r = 0; r < 4; ++r) {
                int row = bm + wm + m * 16 + (lane >> 4) * 4 + r;
                int col = bn + wn + n * 16 + (lane & 15);
                if (row < M && col < N)
                    stf(&C[(size_t)row * N + col], acc[m][n][r]);
            }
        }
    }
}

// ---------------------------------------------------------------------------
// Wide-N variant with the same counted-vmcnt pipeline: 128x256 tile, 8 waves,
// 512 threads, BK=32, 2 bufs (48KB LDS — 3 blocks/CU).  vmcnt(3)/thread-tile.
// ---------------------------------------------------------------------------
template <typename TO>
__global__ __launch_bounds__(512) void gemm_mfma_wide(
    const bf16* __restrict__ A, const bf16* __restrict__ Bt,
    TO* __restrict__ C, int M, int N, int K) {
    __shared__ __align__(16) unsigned short Al[2][128 * 32];
    __shared__ __align__(16) unsigned short Bl[2][256 * 32];
    const int tid = threadIdx.x;
    const int wave = tid >> 6, lane = tid & 63;
    const int wm = (wave >> 2) * 64, wn = (wave & 3) * 64;
    int lin = blockIdx.y * gridDim.x + blockIdx.x;
    const int nwg = gridDim.x * gridDim.y;
    if ((nwg & 7) == 0) lin = (lin & 7) * (nwg >> 3) + (lin >> 3);
    const int bm = (lin / gridDim.x) * 128, bn = (lin % gridDim.x) * 256;
    f32x4 acc[4][4];
#pragma unroll
    for (int m = 0; m < 4; ++m)
#pragma unroll
        for (int n = 0; n < 4; ++n) acc[m][n] = (f32x4)(0.f);

    const int lrow = lane & 15, lk8 = (lane >> 4) * 8;
    const int srow = tid >> 2, sc8 = (tid & 3) * 8;
    auto STAGE = [&](int buf, int k) {  // 3 global_load_lds per thread
        async_copy16((char*)&Al[buf][0] + (size_t)(wave * 64) * 16,
                     A + (size_t)(bm + srow) * K + k + sc8);
        async_copy16((char*)&Bl[buf][0] + (size_t)(wave * 64) * 16,
                     Bt + (size_t)(bn + srow) * K + k + sc8);
        async_copy16((char*)&Bl[buf][0] + (size_t)(512 + wave * 64) * 16,
                     Bt + (size_t)(bn + 128 + srow) * K + k + sc8);
    };
    STAGE(0, 0);
    int cur = 0;
    for (int k0 = 0; k0 < K; k0 += 32) {
        if (k0 + 32 < K) {
            STAGE(cur ^ 1, k0 + 32);
            asm volatile("s_waitcnt vmcnt(3)" ::: "memory");
        } else {
            asm volatile("s_waitcnt vmcnt(0)" ::: "memory");
        }
        __builtin_amdgcn_sched_barrier(0);
        __builtin_amdgcn_s_barrier();
        bf16x8 af[4], bfr[4];
#pragma unroll
        for (int m = 0; m < 4; ++m)
            af[m] = *(const bf16x8*)(&Al[cur][(wm + m * 16 + lrow) * 32 + lk8]);
#pragma unroll
        for (int n = 0; n < 4; ++n)
            bfr[n] = *(const bf16x8*)(&Bl[cur][(wn + n * 16 + lrow) * 32 + lk8]);
#pragma unroll
        for (int m = 0; m < 4; ++m)
#pragma unroll
            for (int n = 0; n < 4; ++n)
                acc[m][n] = __builtin_amdgcn_mfma_f32_16x16x32_bf16(
                    af[m], bfr[n], acc[m][n], 0, 0, 0);
        __builtin_amdgcn_sched_barrier(0);
        __builtin_amdgcn_s_barrier();
        cur ^= 1;
    }
#pragma unroll
    for (int m = 0; m < 4; ++m) {
#pragma unroll
        for (int n = 0; n < 4; ++n) {
#pragma unroll
            for (int r = 0; r < 4; ++r) {
                int row = bm + wm + m * 16 + (lane >> 4) * 4 + r;
                int col = bn + wn + n * 16 + (lane & 15);
                if (row < M && col < N)
                    stf(&C[(size_t)row * N + col], acc[m][n][r]);
            }
        }
    }
}

// ---------------------------------------------------------------------------
// Depthwise conv + bias + silu, register-rolling over an 8-row L-tile.
// ---------------------------------------------------------------------------
__global__ __launch_bounds__(256) void conv_silu_kernel(
    const bf16* __restrict__ xz,
    const float* __restrict__ kx, const float* __restrict__ bx,
    const float* __restrict__ kz, const float* __restrict__ bz,
    bf16* __restrict__ xi, bf16* __restrict__ zo) {
    const int tid = threadIdx.x;
    const int d4 = tid * 4;                    // 0..1020
    const int blk = blockIdx.x;                // BL/8 blocks
    const int l0 = (blk * 8) & (SEQ_L - 1);
    const int b = (blk * 8) >> 12;             // /SEQ_L
    const unsigned short* base = (const unsigned short*)xz +
                                 ((size_t)b * SEQ_L) * (2 * D_INNERn);
    float4 wx[4], wz[4];
#pragma unroll
    for (int k = 0; k < 4; ++k) {
        wx[k] = *(const float4*)(kx + k * D_INNERn + d4);
        wz[k] = *(const float4*)(kz + k * D_INNERn + d4);
    }
    const float4 bxv = *(const float4*)(bx + d4);
    const float4 bzv = *(const float4*)(bz + d4);
    float4 vx[4], vz[4];
#pragma unroll
    for (int j = 0; j < 3; ++j) {
        int l = l0 - 1 + j;
        if (l >= 0) {
            const unsigned short* row = base + (size_t)l * (2 * D_INNERn);
            vx[j] = us4_to_f4(*(const ushort4*)(row + d4));
            vz[j] = us4_to_f4(*(const ushort4*)(row + D_INNERn + d4));
        } else {
            vx[j] = make_float4(0.f, 0.f, 0.f, 0.f);
            vz[j] = make_float4(0.f, 0.f, 0.f, 0.f);
        }
    }
    unsigned short* xout = (unsigned short*)xi;
    unsigned short* zout = (unsigned short*)zo;
#pragma unroll
    for (int j = 0; j < 8; ++j) {
        const int lread = l0 + 2 + j;
        if (lread < SEQ_L) {
            const unsigned short* row = base + (size_t)lread * (2 * D_INNERn);
            vx[3] = us4_to_f4(*(const ushort4*)(row + d4));
            vz[3] = us4_to_f4(*(const ushort4*)(row + D_INNERn + d4));
        } else {
            vx[3] = make_float4(0.f, 0.f, 0.f, 0.f);
            vz[3] = make_float4(0.f, 0.f, 0.f, 0.f);
        }
        float4 ax = bxv, az = bzv;
#pragma unroll
        for (int k = 0; k < 4; ++k) {
            ax.x += vx[k].x * wx[k].x; ax.y += vx[k].y * wx[k].y;
            ax.z += vx[k].z * wx[k].z; ax.w += vx[k].w * wx[k].w;
            az.x += vz[k].x * wz[k].x; az.y += vz[k].y * wz[k].y;
            az.z += vz[k].z * wz[k].z; az.w += vz[k].w * wz[k].w;
        }
        ushort4 ox, oz;
        ox.x = f2b(silu_f(ax.x)); ox.y = f2b(silu_f(ax.y));
        ox.z = f2b(silu_f(ax.z)); ox.w = f2b(silu_f(ax.w));
        oz.x = f2b(silu_f(az.x)); oz.y = f2b(silu_f(az.y));
        oz.z = f2b(silu_f(az.z)); oz.w = f2b(silu_f(az.w));
        const size_t obase = ((size_t)b * SEQ_L + l0 + j) * D_INNERn + d4;
        *(ushort4*)(xout + obase) = ox;
        *(ushort4*)(zout + obase) = oz;
        vx[0] = vx[1]; vx[1] = vx[2]; vx[2] = vx[3];
        vz[0] = vz[1]; vz[1] = vz[2]; vz[2] = vz[3];
    }
}

// ---------------------------------------------------------------------------
// MFMA SSD chunk: per (b,c,h) block, 4 waves.  dt=softplus fused; setprio.
// ---------------------------------------------------------------------------
__global__ __launch_bounds__(256) void ssd_chunk_mfma(
    const unsigned short* __restrict__ xdbl, const bf16* __restrict__ xi,
    const float* __restrict__ dt_bias, const float* __restrict__ A_log,
    const float* __restrict__ Dvec,
    unsigned short* __restrict__ y, unsigned short* __restrict__ S,
    float* __restrict__ acum_g, float* __restrict__ rchunk) {
    __shared__ __align__(16) unsigned short sBb[64 * 72];  // B[s][n]
    __shared__ __align__(16) unsigned short sCb[64 * 72];  // C[l][n]
    __shared__ __align__(16) unsigned short sXT[64 * 72];  // X^T[p][s]
    __shared__ __align__(16) unsigned short sGb[64 * 72];  // G[l][s]
    __shared__ __align__(16) unsigned short sWB[64 * 72];  // (w·B)^T[n][s]
    __shared__ float sdtp[64], sacum[64], sw[64];
    const int bid = blockIdx.x;          // ((b*64 + c)*16 + h)
    const int h = bid & 15;
    const int bc = bid >> 4;
    const int c = bc & (NCHUNK - 1);
    const int b = bc >> 6;
    const int tid = threadIdx.x;
    const int wave = tid >> 6, lane = tid & 63;
    const int lrow = lane & 15, lk8 = (lane >> 4) * 8;
    const int row0 = b * SEQ_L + c * CHUNKn;
    const float Ah = -expf(A_log[h]);
    const float Dh = Dvec[h];

    if (tid < 64) {  // fused dt = softplus(xdbl[..,h] + dt_bias[h])
        float v = b2f(xdbl[(size_t)(row0 + tid) * XDBL_N + h]) + dt_bias[h];
        sdtp[tid] = (v > 20.f) ? v : log1pf(expf(v));
    }
    const unsigned short* xius = (const unsigned short*)xi;
#pragma unroll
    for (int it = 0; it < 16; ++it) {
        int e = tid + it * 256;
        int s = e >> 6, n = e & 63;
        const unsigned short* xr = xdbl + (size_t)(row0 + s) * XDBL_N + N_HEADSn;
        sBb[s * 72 + n] = xr[n];
        sCb[s * 72 + n] = xr[D_STATEn + n];
        sXT[n * 72 + s] = xius[(size_t)(row0 + s) * D_INNERn + h * HEAD_DIMn + n];
    }
    __syncthreads();
    if (wave == 0) {
        float v = Ah * sdtp[lane];
#pragma unroll
        for (int o = 1; o < 64; o <<= 1) {
            float t = __shfl_up(v, o);
            if (lane >= o) v += t;
        }
        sacum[lane] = v;
        float last = __shfl(v, 63);
        sw[lane] = expf(last - v) * sdtp[lane];
        acum_g[(size_t)bid * 64 + lane] = v;
        if (lane == 63) rchunk[bid] = expf(v);
    }
    // MFMA1: Graw = C·B^T
    f32x4 acc1[4];
#pragma unroll
    for (int t = 0; t < 4; ++t) acc1[t] = (f32x4)(0.f);
    __builtin_amdgcn_s_setprio(1);
#pragma unroll
    for (int ks = 0; ks < 2; ++ks) {
        bf16x8 a = *(const bf16x8*)(&sCb[(wave * 16 + lrow) * 72 + ks * 32 + lk8]);
#pragma unroll
        for (int t = 0; t < 4; ++t) {
            bf16x8 bb = *(const bf16x8*)(&sBb[(t * 16 + lrow) * 72 + ks * 32 + lk8]);
            acc1[t] = __builtin_amdgcn_mfma_f32_16x16x32_bf16(a, bb, acc1[t], 0, 0, 0);
        }
    }
    __builtin_amdgcn_s_setprio(0);
    __syncthreads();
#pragma unroll
    for (int t = 0; t < 4; ++t) {
#pragma unroll
        for (int r = 0; r < 4; ++r) {
            int l = wave * 16 + (lane >> 4) * 4 + r;
            int s = t * 16 + lrow;
            float val = 0.f;
            if (l >= s) val = acc1[t][r] * expf(sacum[l] - sacum[s]) * sdtp[s];
            sGb[l * 72 + s] = f2b(val);
        }
    }
#pragma unroll
    for (int it = 0; it < 16; ++it) {
        int e = tid + it * 256;
        int s = e >> 6, n = e & 63;
        sWB[n * 72 + s] = f2b(sw[s] * b2f(sBb[s * 72 + n]));
    }
    __syncthreads();
    f32x4 acc2[4], acc3[4];
#pragma unroll
    for (int t = 0; t < 4; ++t) { acc2[t] = (f32x4)(0.f); acc3[t] = (f32x4)(0.f); }
    __builtin_amdgcn_s_setprio(1);
#pragma unroll
    for (int ks = 0; ks < 2; ++ks) {
        bf16x8 a2 = *(const bf16x8*)(&sGb[(wave * 16 + lrow) * 72 + ks * 32 + lk8]);
        bf16x8 a3 = *(const bf16x8*)(&sXT[(wave * 16 + lrow) * 72 + ks * 32 + lk8]);
#pragma unroll
        for (int t = 0; t < 4; ++t) {
            bf16x8 b2v = *(const bf16x8*)(&sXT[(t * 16 + lrow) * 72 + ks * 32 + lk8]);
            bf16x8 b3v = *(const bf16x8*)(&sWB[(t * 16 + lrow) * 72 + ks * 32 + lk8]);
            acc2[t] = __builtin_amdgcn_mfma_f32_16x16x32_bf16(a2, b2v, acc2[t], 0, 0, 0);
            acc3[t] = __builtin_amdgcn_mfma_f32_16x16x32_bf16(a3, b3v, acc3[t], 0, 0, 0);
        }
    }
    __builtin_amdgcn_s_setprio(0);
#pragma unroll
    for (int t = 0; t < 4; ++t) {
#pragma unroll
        for (int r = 0; r < 4; ++r) {
            int rr = wave * 16 + (lane >> 4) * 4 + r;
            int cc = t * 16 + lrow;
            float xv = b2f(sXT[cc * 72 + rr]);
            y[(size_t)(row0 + rr) * D_INNERn + h * HEAD_DIMn + cc] =
                f2b(acc2[t][r] + Dh * xv);
            S[(size_t)bid * 4096 + rr * 64 + cc] = f2b(acc3[t][r]);
        }
    }
}

// ---------------------------------------------------------------------------
// Inter-chunk scan (bf16 S, f32 running state): S[c] <- state ENTERING c.
// ---------------------------------------------------------------------------
__global__ __launch_bounds__(256) void chunk_scan_kernel(
    unsigned short* __restrict__ S, const float* __restrict__ rchunk) {
    const int idx = blockIdx.x * 256 + threadIdx.x;  // BH * 2048
    const int pn2 = (idx & 2047) * 2;
    const int bh = idx >> 11;
    const int h = bh & 15;
    const int b = bh >> 4;
    float P0 = 0.f, P1 = 0.f;
    for (int c = 0; c < NCHUNK; ++c) {
        int bid = (b * NCHUNK + c) * N_HEADSn + h;
        size_t off = (size_t)bid * 4096 + pn2;
        unsigned int v = *(unsigned int*)(S + off);
        float s0 = b2f((unsigned short)(v & 0xffff));
        float s1 = b2f((unsigned short)(v >> 16));
        *(unsigned int*)(S + off) =
            (unsigned int)f2b(P0) | ((unsigned int)f2b(P1) << 16);
        float rc = rchunk[bid];
        P0 = rc * P0 + s0;
        P1 = rc * P1 + s1;
    }
}

// ---------------------------------------------------------------------------
// MFMA Y_off: y[l][p] += exp(acum[l]) * sum_n C[l][n] * P[p][n]  (all bf16)
// ---------------------------------------------------------------------------
__global__ __launch_bounds__(256) void yoff_mfma(
    const unsigned short* __restrict__ xdbl, const unsigned short* __restrict__ S,
    const float* __restrict__ acum_g, unsigned short* __restrict__ y) {
    __shared__ __align__(16) unsigned short sCb[64 * 72];
    __shared__ __align__(16) unsigned short sP[64 * 72];
    __shared__ float se[64];
    const int bid = blockIdx.x;
    const int h = bid & 15;
    const int bc = bid >> 4;
    const int c = bc & (NCHUNK - 1);
    const int b = bc >> 6;
    const int tid = threadIdx.x;
    const int wave = tid >> 6, lane = tid & 63;
    const int lrow = lane & 15, lk8 = (lane >> 4) * 8;
    const int row0 = b * SEQ_L + c * CHUNKn;
    if (tid < 64) se[tid] = expf(acum_g[(size_t)bid * 64 + tid]);
#pragma unroll
    for (int it = 0; it < 16; ++it) {
        int e = tid + it * 256;
        int r = e >> 6, n = e & 63;
        sCb[r * 72 + n] = xdbl[(size_t)(row0 + r) * XDBL_N + N_HEADSn + D_STATEn + n];
        sP[r * 72 + n] = S[(size_t)bid * 4096 + e];
    }
    __syncthreads();
    f32x4 acc[4];
#pragma unroll
    for (int t = 0; t < 4; ++t) acc[t] = (f32x4)(0.f);
    __builtin_amdgcn_s_setprio(1);
#pragma unroll
    for (int ks = 0; ks < 2; ++ks) {
        bf16x8 a = *(const bf16x8*)(&sCb[(wave * 16 + lrow) * 72 + ks * 32 + lk8]);
#pragma unroll
        for (int t = 0; t < 4; ++t) {
            bf16x8 bb = *(const bf16x8*)(&sP[(t * 16 + lrow) * 72 + ks * 32 + lk8]);
            acc[t] = __builtin_amdgcn_mfma_f32_16x16x32_bf16(a, bb, acc[t], 0, 0, 0);
        }
    }
    __builtin_amdgcn_s_setprio(0);
#pragma unroll
    for (int t = 0; t < 4; ++t) {
#pragma unroll
        for (int r = 0; r < 4; ++r) {
            int l = wave * 16 + (lane >> 4) * 4 + r;
            int p = t * 16 + lrow;
            size_t idx = (size_t)(row0 + l) * D_INNERn + h * HEAD_DIMn + p;
            y[idx] = f2b(b2f(y[idx]) + acc[t][r] * se[l]);
        }
    }
}

// ---------------------------------------------------------------------------
// y_bf = bf16( RMSNorm(y * silu(z)) * norm_weight )   (y input bf16)
// ---------------------------------------------------------------------------
__global__ __launch_bounds__(256) void gate_norm_kernel(
    const unsigned short* __restrict__ y, const bf16* __restrict__ zb,
    const float* __restrict__ nw, bf16* __restrict__ y_bf) {
    const int row = blockIdx.x;
    const int tid = threadIdx.x;
    const size_t base = (size_t)row * D_INNERn + tid * 4;
    ushort4 yu = *(const ushort4*)(y + base);
    ushort4 zu = *(const ushort4*)((const unsigned short*)zb + base);
    float v0 = b2f(yu.x) * silu_f(b2f(zu.x));
    float v1 = b2f(yu.y) * silu_f(b2f(zu.y));
    float v2 = b2f(yu.z) * silu_f(b2f(zu.z));
    float v3 = b2f(yu.w) * silu_f(b2f(zu.w));
    float ss = v0 * v0 + v1 * v1 + v2 * v2 + v3 * v3;
#pragma unroll
    for (int o = 32; o > 0; o >>= 1) ss += __shfl_xor(ss, o);
    __shared__ float sred[4];
    if ((tid & 63) == 0) sred[tid >> 6] = ss;
    __syncthreads();
    float total = sred[0] + sred[1] + sred[2] + sred[3];
    float scale = rsqrtf(total * (1.0f / D_INNERn) + 1e-5f);
    float4 wv = *(const float4*)(nw + tid * 4);
    ushort4 o4;
    o4.x = f2b(v0 * scale * wv.x);
    o4.y = f2b(v1 * scale * wv.y);
    o4.z = f2b(v2 * scale * wv.z);
    o4.w = f2b(v3 * scale * wv.w);
    *(ushort4*)((unsigned short*)y_bf + base) = o4;
}

// ---------------------------------------------------------------------------
extern "C" void kernel_launch(void* const* d_in, const int* in_sizes, int n_in,
                              void* d_out, int out_size, void* d_ws, size_t ws_size,
                              hipStream_t stream) {
    (void)in_sizes; (void)n_in; (void)out_size; (void)ws_size;
    const float* x       = (const float*)d_in[0];
    const float* W_in    = (const float*)d_in[1];
    const float* ckx     = (const float*)d_in[2];
    const float* cbx     = (const float*)d_in[3];
    const float* ckz     = (const float*)d_in[4];
    const float* cbz     = (const float*)d_in[5];
    const float* W_xdbl  = (const float*)d_in[6];
    const float* dt_bias = (const float*)d_in[7];
    const float* A_log   = (const float*)d_in[8];
    const float* Dvec    = (const float*)d_in[9];
    const float* nw      = (const float*)d_in[10];
    const float* W_out   = (const float*)d_in[11];
    float* out = (float*)d_out;   // f32 output (round-6 verified)
    char* w = (char*)d_ws;

    // Workspace layout (bytes), total 212,877,312 — proven size.
    bf16*  xz     = (bf16*)(w);               // [BL][2048] bf16 = 67,108,864
    unsigned short* y = (unsigned short*)(w); // alias: bf16 [BL][1024] (xz dead)
    bf16*  xi     = (bf16*)(w + 67108864);    // [BL][1024] bf16 = 33,554,432
    bf16*  zb     = (bf16*)(w + 100663296);   // [BL][1024] bf16 = 33,554,432
    char*  Sreg   = w + 134217728;            // 67,108,864 region, multi-use:
    unsigned short* S = (unsigned short*)Sreg;//   [4096][4096] bf16 = 33.5M (SSD)
    bf16*  x_bf   = (bf16*)Sreg;              //   prologue: [BL][512] bf16 = 16.8M
    bf16*  W_in_T = (bf16*)(Sreg + 16777216); //   prologue: [2048][512] bf16 = 2.1M
    bf16*  W_xd_T = (bf16*)(Sreg + 18874368); //   prologue: [144][1024] bf16 = 0.3M
    bf16*  y_bf   = (bf16*)Sreg;              //   epilogue: [BL][1024] bf16 = 33.5M
    bf16*  W_o_T  = (bf16*)(Sreg + 33554432); //   epilogue: [512][1024] bf16 = 1.0M
    unsigned short* xdbl = (unsigned short*)(w + 201326592);  // [BL][144] bf16 = 4.7M
    float* acum   = (float*)(w + 211812352);  // [4096][64] f32  =  1,048,576
    float* rchunk = (float*)(w + 212860928);  // [4096] f32      =     16,384

    // 0. prologue converts (into S region — dead until ssd_chunk)
    cvt_f32_bf16<<<BL * D_MODELn / 1024, 256, 0, stream>>>(x, x_bf);
    transpose_cvt<<<dim3(2048 / 32, 512 / 32), 256, 0, stream>>>(W_in, W_in_T, 512, 2048);
    transpose_cvt<<<dim3(5, 1024 / 32), 256, 0, stream>>>(W_xdbl, W_xd_T, 1024, 144);
    // 1. xz = x @ W_in  (MFMA wide, counted-vmcnt pipeline), store bf16
    gemm_mfma_wide<bf16><<<dim3(2048 / 256, BL / 128), 512, 0, stream>>>(
        x_bf, W_in_T, xz, BL, 2048, D_MODELn);
    // 2. conv + silu -> xi, zb (register-rolling 8-row tile)
    conv_silu_kernel<<<BL / 8, 256, 0, stream>>>(xz, ckx, cbx, ckz, cbz, xi, zb);
    // 3. x_dbl = xi @ W_xdbl  (MFMA 128², counted-vmcnt), bf16 out
    gemm_mfma<bf16><<<dim3(2, BL / 128), 256, 0, stream>>>(
        xi, W_xd_T, (bf16*)xdbl, BL, XDBL_N, D_INNERn);
    // 4+5. SSD per-chunk (MFMA, dt fused, setprio): Y_diag + states
    ssd_chunk_mfma<<<B_SZn * NCHUNK * N_HEADSn, 256, 0, stream>>>(
        xdbl, xi, dt_bias, A_log, Dvec, y, S, acum, rchunk);
    // 6. inter-chunk scan (in place, bf16)
    chunk_scan_kernel<<<B_SZn * N_HEADSn * 2048 / 256, 256, 0, stream>>>(S, rchunk);
    // 7. Y_off accumulate (MFMA, bf16 RMW, setprio)
    yoff_mfma<<<B_SZn * NCHUNK * N_HEADSn, 256, 0, stream>>>(xdbl, S, acum, y);
    // 8. epilogue: W_out^T (S dead after yoff), gate+norm -> y_bf
    transpose_cvt<<<dim3(512 / 32, 1024 / 32), 256, 0, stream>>>(W_out, W_o_T, 1024, 512);
    gate_norm_kernel<<<BL, 256, 0, stream>>>(y, zb, nw, y_bf);
    // 9. out = y @ W_out  (MFMA 128², counted-vmcnt, 512 blocks), store f32
    gemm_mfma<float><<<dim3(512 / 128, BL / 128), 256, 0, stream>>>(
        y_bf, W_o_T, out, BL, D_MODELn, D_INNERn);
}

// Round 17
// 243.183 us; speedup vs baseline: 1.0090x; 1.0090x over previous
//
#include <hip/hip_runtime.h>
#include <hip/hip_bf16.h>
#include <cstdint>

#define B_SZn 4
#define SEQ_L 4096
#define D_MODELn 512
#define D_INNERn 1024
#define N_HEADSn 16
#define HEAD_DIMn 64
#define D_STATEn 64
#define CHUNKn 64
#define NCHUNK (SEQ_L / CHUNKn)          // 64
#define BL (B_SZn * SEQ_L)               // 16384
#define XDBL_N (N_HEADSn + 2 * D_STATEn) // 144

typedef __hip_bfloat16 bf16;
typedef __bf16 bf16x8 __attribute__((ext_vector_type(8)));
typedef float f32x4 __attribute__((ext_vector_type(4)));

__device__ __forceinline__ float silu_f(float v) {
    return v / (1.0f + expf(-v));
}
__device__ __forceinline__ float b2f(unsigned short u) {
    return __uint_as_float((unsigned)u << 16);
}
__device__ __forceinline__ unsigned short f2b(float f) {
    bf16 h = __float2bfloat16(f);
    return *(unsigned short*)&h;
}
__device__ __forceinline__ void stf(float* p, float v) { *p = v; }
__device__ __forceinline__ void stf(bf16* p, float v) { *p = __float2bfloat16(v); }

__device__ __forceinline__ float4 us4_to_f4(ushort4 u) {
    float4 f;
    f.x = b2f(u.x); f.y = b2f(u.y); f.z = b2f(u.z); f.w = b2f(u.w);
    return f;
}

// async global->LDS 16B copy (m97/m193-proven pattern).
__device__ __forceinline__ void async_copy16(void* lds, const void* g) {
    __builtin_amdgcn_global_load_lds(
        (const __attribute__((address_space(1))) unsigned int*)g,
        (__attribute__((address_space(3))) unsigned int*)lds, 16, 0, 0);
}

// ---------------------------------------------------------------------------
// x (f32) -> bf16 elementwise convert
// ---------------------------------------------------------------------------
__global__ __launch_bounds__(256) void cvt_f32_bf16(
    const float* __restrict__ in, bf16* __restrict__ out) {
    const int idx = blockIdx.x * 256 + threadIdx.x;
    float4 v = *(const float4*)(in + (size_t)idx * 4);
    ushort4 o;
    o.x = f2b(v.x); o.y = f2b(v.y); o.z = f2b(v.z); o.w = f2b(v.w);
    *(ushort4*)((unsigned short*)out + (size_t)idx * 4) = o;
}

// ---------------------------------------------------------------------------
// Transpose + convert: out[c][r] = bf16(in[r][c]).  in [R][C] f32.
// ---------------------------------------------------------------------------
__global__ __launch_bounds__(256) void transpose_cvt(
    const float* __restrict__ in, bf16* __restrict__ out, int R, int C) {
    __shared__ float t[32][33];
    const int bc = blockIdx.x * 32, br = blockIdx.y * 32;
    const int tx = threadIdx.x & 31, ty = threadIdx.x >> 5;  // ty 0..7
#pragma unroll
    for (int i = ty; i < 32; i += 8) {
        int r = br + i, c = bc + tx;
        t[i][tx] = (r < R && c < C) ? in[(size_t)r * C + c] : 0.f;
    }
    __syncthreads();
#pragma unroll
    for (int i = ty; i < 32; i += 8) {
        int c = bc + i, r = br + tx;
        if (c < C && r < R) out[(size_t)c * R + r] = __float2bfloat16(t[tx][i]);
    }
}

// ---------------------------------------------------------------------------
// bf16 MFMA GEMM (r12/r14-proven best): C[M,N] = A[M,K] @ Bt[N,K]^T.
// 128x128 tile, BK=64 as two 32-wide half-subtiles, single-buffered
// global_load_lds staging, XCD-aware block swizzle (T1).  4 waves, 32KB LDS.
// ---------------------------------------------------------------------------
template <typename TO>
__global__ __launch_bounds__(256) void gemm_mfma(
    const bf16* __restrict__ A, const bf16* __restrict__ Bt,
    TO* __restrict__ C, int M, int N, int K) {
    __shared__ __align__(16) unsigned short Al[2][128 * 32];
    __shared__ __align__(16) unsigned short Bl[2][128 * 32];
    const int tid = threadIdx.x;
    const int wave = tid >> 6, lane = tid & 63;
    const int wm = (wave >> 1) * 64, wn = (wave & 1) * 64;
    int lin = blockIdx.y * gridDim.x + blockIdx.x;
    const int nwg = gridDim.x * gridDim.y;
    if ((nwg & 7) == 0) lin = (lin & 7) * (nwg >> 3) + (lin >> 3);
    const int bm = (lin / gridDim.x) * 128, bn = (lin % gridDim.x) * 128;
    f32x4 acc[4][4];
#pragma unroll
    for (int m = 0; m < 4; ++m)
#pragma unroll
        for (int n = 0; n < 4; ++n) acc[m][n] = (f32x4)(0.f);

    const int lrow = lane & 15, lk8 = (lane >> 4) * 8;
    const int srow = tid >> 2, sc8 = (tid & 3) * 8;
    for (int k0 = 0; k0 < K; k0 += 64) {
#pragma unroll
        for (int h = 0; h < 2; ++h) {
            const int kh = k0 + h * 32;
            async_copy16((char*)&Al[h][0] + (size_t)(wave * 64) * 16,
                         A + (size_t)(bm + srow) * K + kh + sc8);
            async_copy16((char*)&Al[h][0] + (size_t)(256 + wave * 64) * 16,
                         A + (size_t)(bm + 64 + srow) * K + kh + sc8);
            async_copy16((char*)&Bl[h][0] + (size_t)(wave * 64) * 16,
                         Bt + (size_t)(bn + srow) * K + kh + sc8);
            async_copy16((char*)&Bl[h][0] + (size_t)(256 + wave * 64) * 16,
                         Bt + (size_t)(bn + 64 + srow) * K + kh + sc8);
        }
        __syncthreads();
#pragma unroll
        for (int h = 0; h < 2; ++h) {
            bf16x8 af[4], bfr[4];
#pragma unroll
            for (int m = 0; m < 4; ++m)
                af[m] = *(const bf16x8*)(&Al[h][(wm + m * 16 + lrow) * 32 + lk8]);
#pragma unroll
            for (int n = 0; n < 4; ++n)
                bfr[n] = *(const bf16x8*)(&Bl[h][(wn + n * 16 + lrow) * 32 + lk8]);
#pragma unroll
            for (int m = 0; m < 4; ++m)
#pragma unroll
                for (int n = 0; n < 4; ++n)
                    acc[m][n] = __builtin_amdgcn_mfma_f32_16x16x32_bf16(
                        af[m], bfr[n], acc[m][n], 0, 0, 0);
        }
        __syncthreads();
    }
#pragma unroll
    for (int m = 0; m < 4; ++m) {
#pragma unroll
        for (int n = 0; n < 4; ++n) {
#pragma unroll
            for (int r = 0; r < 4; ++r) {
                int row = bm + wm + m * 16 + (lane >> 4) * 4 + r;
                int col = bn + wn + n * 16 + (lane & 15);
                if (row < M && col < N)
                    stf(&C[(size_t)row * N + col], acc[m][n][r]);
            }
        }
    }
}

// ---------------------------------------------------------------------------
// Wide-N variant (r14-proven for GEMM1): 128x256 tile, 8 waves (2Mx4N),
// 512 threads, BK=64 half-split, 48KB LDS (3 blocks/CU).
// ---------------------------------------------------------------------------
template <typename TO>
__global__ __launch_bounds__(512) void gemm_mfma_wide(
    const bf16* __restrict__ A, const bf16* __restrict__ Bt,
    TO* __restrict__ C, int M, int N, int K) {
    __shared__ __align__(16) unsigned short Al[2][128 * 32];
    __shared__ __align__(16) unsigned short Bl[2][256 * 32];
    const int tid = threadIdx.x;
    const int wave = tid >> 6, lane = tid & 63;
    const int wm = (wave >> 2) * 64, wn = (wave & 3) * 64;
    int lin = blockIdx.y * gridDim.x + blockIdx.x;
    const int nwg = gridDim.x * gridDim.y;
    if ((nwg & 7) == 0) lin = (lin & 7) * (nwg >> 3) + (lin >> 3);
    const int bm = (lin / gridDim.x) * 128, bn = (lin % gridDim.x) * 256;
    f32x4 acc[4][4];
#pragma unroll
    for (int m = 0; m < 4; ++m)
#pragma unroll
        for (int n = 0; n < 4; ++n) acc[m][n] = (f32x4)(0.f);

    const int lrow = lane & 15, lk8 = (lane >> 4) * 8;
    const int srow = tid >> 2, sc8 = (tid & 3) * 8;  // 512 thr: A 1 seg, B 2 segs
    for (int k0 = 0; k0 < K; k0 += 64) {
#pragma unroll
        for (int h = 0; h < 2; ++h) {
            const int kh = k0 + h * 32;
            async_copy16((char*)&Al[h][0] + (size_t)(wave * 64) * 16,
                         A + (size_t)(bm + srow) * K + kh + sc8);
            async_copy16((char*)&Bl[h][0] + (size_t)(wave * 64) * 16,
                         Bt + (size_t)(bn + srow) * K + kh + sc8);
            async_copy16((char*)&Bl[h][0] + (size_t)(512 + wave * 64) * 16,
                         Bt + (size_t)(bn + 128 + srow) * K + kh + sc8);
        }
        __syncthreads();
#pragma unroll
        for (int h = 0; h < 2; ++h) {
            bf16x8 af[4], bfr[4];
#pragma unroll
            for (int m = 0; m < 4; ++m)
                af[m] = *(const bf16x8*)(&Al[h][(wm + m * 16 + lrow) * 32 + lk8]);
#pragma unroll
            for (int n = 0; n < 4; ++n)
                bfr[n] = *(const bf16x8*)(&Bl[h][(wn + n * 16 + lrow) * 32 + lk8]);
#pragma unroll
            for (int m = 0; m < 4; ++m)
#pragma unroll
                for (int n = 0; n < 4; ++n)
                    acc[m][n] = __builtin_amdgcn_mfma_f32_16x16x32_bf16(
                        af[m], bfr[n], acc[m][n], 0, 0, 0);
        }
        __syncthreads();
    }
#pragma unroll
    for (int m = 0; m < 4; ++m) {
#pragma unroll
        for (int n = 0; n < 4; ++n) {
#pragma unroll
            for (int r = 0; r < 4; ++r) {
                int row = bm + wm + m * 16 + (lane >> 4) * 4 + r;
                int col = bn + wn + n * 16 + (lane & 15);
                if (row < M && col < N)
                    stf(&C[(size_t)row * N + col], acc[m][n][r]);
            }
        }
    }
}

// ---------------------------------------------------------------------------
// Depthwise conv + bias + silu, register-rolling over a 16-row L-tile.
// 19 row-reads per 16 outputs (1.19x overfetch, was 1.375x at 8 rows).
// 1024 blocks = 4/CU.
// ---------------------------------------------------------------------------
__global__ __launch_bounds__(256) void conv_silu_kernel(
    const bf16* __restrict__ xz,
    const float* __restrict__ kx, const float* __restrict__ bx,
    const float* __restrict__ kz, const float* __restrict__ bz,
    bf16* __restrict__ xi, bf16* __restrict__ zo) {
    const int tid = threadIdx.x;
    const int d4 = tid * 4;                    // 0..1020
    const int blk = blockIdx.x;                // BL/16 blocks
    const int l0 = (blk * 16) & (SEQ_L - 1);
    const int b = (blk * 16) >> 12;            // /SEQ_L
    const unsigned short* base = (const unsigned short*)xz +
                                 ((size_t)b * SEQ_L) * (2 * D_INNERn);
    float4 wx[4], wz[4];
#pragma unroll
    for (int k = 0; k < 4; ++k) {
        wx[k] = *(const float4*)(kx + k * D_INNERn + d4);
        wz[k] = *(const float4*)(kz + k * D_INNERn + d4);
    }
    const float4 bxv = *(const float4*)(bx + d4);
    const float4 bzv = *(const float4*)(bz + d4);
    float4 vx[4], vz[4];
#pragma unroll
    for (int j = 0; j < 3; ++j) {
        int l = l0 - 1 + j;
        if (l >= 0) {
            const unsigned short* row = base + (size_t)l * (2 * D_INNERn);
            vx[j] = us4_to_f4(*(const ushort4*)(row + d4));
            vz[j] = us4_to_f4(*(const ushort4*)(row + D_INNERn + d4));
        } else {
            vx[j] = make_float4(0.f, 0.f, 0.f, 0.f);
            vz[j] = make_float4(0.f, 0.f, 0.f, 0.f);
        }
    }
    unsigned short* xout = (unsigned short*)xi;
    unsigned short* zout = (unsigned short*)zo;
#pragma unroll
    for (int j = 0; j < 16; ++j) {
        const int lread = l0 + 2 + j;
        if (lread < SEQ_L) {
            const unsigned short* row = base + (size_t)lread * (2 * D_INNERn);
            vx[3] = us4_to_f4(*(const ushort4*)(row + d4));
            vz[3] = us4_to_f4(*(const ushort4*)(row + D_INNERn + d4));
        } else {
            vx[3] = make_float4(0.f, 0.f, 0.f, 0.f);
            vz[3] = make_float4(0.f, 0.f, 0.f, 0.f);
        }
        float4 ax = bxv, az = bzv;
#pragma unroll
        for (int k = 0; k < 4; ++k) {
            ax.x += vx[k].x * wx[k].x; ax.y += vx[k].y * wx[k].y;
            ax.z += vx[k].z * wx[k].z; ax.w += vx[k].w * wx[k].w;
            az.x += vz[k].x * wz[k].x; az.y += vz[k].y * wz[k].y;
            az.z += vz[k].z * wz[k].z; az.w += vz[k].w * wz[k].w;
        }
        ushort4 ox, oz;
        ox.x = f2b(silu_f(ax.x)); ox.y = f2b(silu_f(ax.y));
        ox.z = f2b(silu_f(ax.z)); ox.w = f2b(silu_f(ax.w));
        oz.x = f2b(silu_f(az.x)); oz.y = f2b(silu_f(az.y));
        oz.z = f2b(silu_f(az.z)); oz.w = f2b(silu_f(az.w));
        const size_t obase = ((size_t)b * SEQ_L + l0 + j) * D_INNERn + d4;
        *(ushort4*)(xout + obase) = ox;
        *(ushort4*)(zout + obase) = oz;
        vx[0] = vx[1]; vx[1] = vx[2]; vx[2] = vx[3];
        vz[0] = vz[1]; vz[1] = vz[2]; vz[2] = vz[3];
    }
}

// ---------------------------------------------------------------------------
// MFMA SSD chunk: per (b,c,h) block, 4 waves.  dt=softplus fused; setprio.
// ---------------------------------------------------------------------------
__global__ __launch_bounds__(256) void ssd_chunk_mfma(
    const unsigned short* __restrict__ xdbl, const bf16* __restrict__ xi,
    const float* __restrict__ dt_bias, const float* __restrict__ A_log,
    const float* __restrict__ Dvec,
    unsigned short* __restrict__ y, unsigned short* __restrict__ S,
    float* __restrict__ acum_g, float* __restrict__ rchunk) {
    __shared__ __align__(16) unsigned short sBb[64 * 72];  // B[s][n]
    __shared__ __align__(16) unsigned short sCb[64 * 72];  // C[l][n]
    __shared__ __align__(16) unsigned short sXT[64 * 72];  // X^T[p][s]
    __shared__ __align__(16) unsigned short sGb[64 * 72];  // G[l][s]
    __shared__ __align__(16) unsigned short sWB[64 * 72];  // (w·B)^T[n][s]
    __shared__ float sdtp[64], sacum[64], sw[64];
    const int bid = blockIdx.x;          // ((b*64 + c)*16 + h)
    const int h = bid & 15;
    const int bc = bid >> 4;
    const int c = bc & (NCHUNK - 1);
    const int b = bc >> 6;
    const int tid = threadIdx.x;
    const int wave = tid >> 6, lane = tid & 63;
    const int lrow = lane & 15, lk8 = (lane >> 4) * 8;
    const int row0 = b * SEQ_L + c * CHUNKn;
    const float Ah = -expf(A_log[h]);
    const float Dh = Dvec[h];

    if (tid < 64) {  // fused dt = softplus(xdbl[..,h] + dt_bias[h])
        float v = b2f(xdbl[(size_t)(row0 + tid) * XDBL_N + h]) + dt_bias[h];
        sdtp[tid] = (v > 20.f) ? v : log1pf(expf(v));
    }
    const unsigned short* xius = (const unsigned short*)xi;
#pragma unroll
    for (int it = 0; it < 16; ++it) {
        int e = tid + it * 256;
        int s = e >> 6, n = e & 63;
        const unsigned short* xr = xdbl + (size_t)(row0 + s) * XDBL_N + N_HEADSn;
        sBb[s * 72 + n] = xr[n];
        sCb[s * 72 + n] = xr[D_STATEn + n];
        sXT[n * 72 + s] = xius[(size_t)(row0 + s) * D_INNERn + h * HEAD_DIMn + n];
    }
    __syncthreads();
    if (wave == 0) {
        float v = Ah * sdtp[lane];
#pragma unroll
        for (int o = 1; o < 64; o <<= 1) {
            float t = __shfl_up(v, o);
            if (lane >= o) v += t;
        }
        sacum[lane] = v;
        float last = __shfl(v, 63);
        sw[lane] = expf(last - v) * sdtp[lane];
        acum_g[(size_t)bid * 64 + lane] = v;
        if (lane == 63) rchunk[bid] = expf(v);
    }
    // MFMA1: Graw = C·B^T
    f32x4 acc1[4];
#pragma unroll
    for (int t = 0; t < 4; ++t) acc1[t] = (f32x4)(0.f);
    __builtin_amdgcn_s_setprio(1);
#pragma unroll
    for (int ks = 0; ks < 2; ++ks) {
        bf16x8 a = *(const bf16x8*)(&sCb[(wave * 16 + lrow) * 72 + ks * 32 + lk8]);
#pragma unroll
        for (int t = 0; t < 4; ++t) {
            bf16x8 bb = *(const bf16x8*)(&sBb[(t * 16 + lrow) * 72 + ks * 32 + lk8]);
            acc1[t] = __builtin_amdgcn_mfma_f32_16x16x32_bf16(a, bb, acc1[t], 0, 0, 0);
        }
    }
    __builtin_amdgcn_s_setprio(0);
    __syncthreads();
#pragma unroll
    for (int t = 0; t < 4; ++t) {
#pragma unroll
        for (int r = 0; r < 4; ++r) {
            int l = wave * 16 + (lane >> 4) * 4 + r;
            int s = t * 16 + lrow;
            float val = 0.f;
            if (l >= s) val = acc1[t][r] * expf(sacum[l] - sacum[s]) * sdtp[s];
            sGb[l * 72 + s] = f2b(val);
        }
    }
#pragma unroll
    for (int it = 0; it < 16; ++it) {
        int e = tid + it * 256;
        int s = e >> 6, n = e & 63;
        sWB[n * 72 + s] = f2b(sw[s] * b2f(sBb[s * 72 + n]));
    }
    __syncthreads();
    f32x4 acc2[4], acc3[4];
#pragma unroll
    for (int t = 0; t < 4; ++t) { acc2[t] = (f32x4)(0.f); acc3[t] = (f32x4)(0.f); }
    __builtin_amdgcn_s_setprio(1);
#pragma unroll
    for (int ks = 0; ks < 2; ++ks) {
        bf16x8 a2 = *(const bf16x8*)(&sGb[(wave * 16 + lrow) * 72 + ks * 32 + lk8]);
        bf16x8 a3 = *(const bf16x8*)(&sXT[(wave * 16 + lrow) * 72 + ks * 32 + lk8]);
#pragma unroll
        for (int t = 0; t < 4; ++t) {
            bf16x8 b2v = *(const bf16x8*)(&sXT[(t * 16 + lrow) * 72 + ks * 32 + lk8]);
            bf16x8 b3v = *(const bf16x8*)(&sWB[(t * 16 + lrow) * 72 + ks * 32 + lk8]);
            acc2[t] = __builtin_amdgcn_mfma_f32_16x16x32_bf16(a2, b2v, acc2[t], 0, 0, 0);
            acc3[t] = __builtin_amdgcn_mfma_f32_16x16x32_bf16(a3, b3v, acc3[t], 0, 0, 0);
        }
    }
    __builtin_amdgcn_s_setprio(0);
#pragma unroll
    for (int t = 0; t < 4; ++t) {
#pragma unroll
        for (int r = 0; r < 4; ++r) {
            int rr = wave * 16 + (lane >> 4) * 4 + r;
            int cc = t * 16 + lrow;
            float xv = b2f(sXT[cc * 72 + rr]);
            y[(size_t)(row0 + rr) * D_INNERn + h * HEAD_DIMn + cc] =
                f2b(acc2[t][r] + Dh * xv);
            S[(size_t)bid * 4096 + rr * 64 + cc] = f2b(acc3[t][r]);
        }
    }
}

// ---------------------------------------------------------------------------
// Inter-chunk scan (bf16 S, f32 running state): S[c] <- state ENTERING c.
// ---------------------------------------------------------------------------
__global__ __launch_bounds__(256) void chunk_scan_kernel(
    unsigned short* __restrict__ S, const float* __restrict__ rchunk) {
    const int idx = blockIdx.x * 256 + threadIdx.x;  // BH * 2048
    const int pn2 = (idx & 2047) * 2;
    const int bh = idx >> 11;
    const int h = bh & 15;
    const int b = bh >> 4;
    float P0 = 0.f, P1 = 0.f;
    for (int c = 0; c < NCHUNK; ++c) {
        int bid = (b * NCHUNK + c) * N_HEADSn + h;
        size_t off = (size_t)bid * 4096 + pn2;
        unsigned int v = *(unsigned int*)(S + off);
        float s0 = b2f((unsigned short)(v & 0xffff));
        float s1 = b2f((unsigned short)(v >> 16));
        *(unsigned int*)(S + off) =
            (unsigned int)f2b(P0) | ((unsigned int)f2b(P1) << 16);
        float rc = rchunk[bid];
        P0 = rc * P0 + s0;
        P1 = rc * P1 + s1;
    }
}

// ---------------------------------------------------------------------------
// MFMA Y_off: y[l][p] += exp(acum[l]) * sum_n C[l][n] * P[p][n]  (all bf16)
// ---------------------------------------------------------------------------
__global__ __launch_bounds__(256) void yoff_mfma(
    const unsigned short* __restrict__ xdbl, const unsigned short* __restrict__ S,
    const float* __restrict__ acum_g, unsigned short* __restrict__ y) {
    __shared__ __align__(16) unsigned short sCb[64 * 72];
    __shared__ __align__(16) unsigned short sP[64 * 72];
    __shared__ float se[64];
    const int bid = blockIdx.x;
    const int h = bid & 15;
    const int bc = bid >> 4;
    const int c = bc & (NCHUNK - 1);
    const int b = bc >> 6;
    const int tid = threadIdx.x;
    const int wave = tid >> 6, lane = tid & 63;
    const int lrow = lane & 15, lk8 = (lane >> 4) * 8;
    const int row0 = b * SEQ_L + c * CHUNKn;
    if (tid < 64) se[tid] = expf(acum_g[(size_t)bid * 64 + tid]);
#pragma unroll
    for (int it = 0; it < 16; ++it) {
        int e = tid + it * 256;
        int r = e >> 6, n = e & 63;
        sCb[r * 72 + n] = xdbl[(size_t)(row0 + r) * XDBL_N + N_HEADSn + D_STATEn + n];
        sP[r * 72 + n] = S[(size_t)bid * 4096 + e];
    }
    __syncthreads();
    f32x4 acc[4];
#pragma unroll
    for (int t = 0; t < 4; ++t) acc[t] = (f32x4)(0.f);
    __builtin_amdgcn_s_setprio(1);
#pragma unroll
    for (int ks = 0; ks < 2; ++ks) {
        bf16x8 a = *(const bf16x8*)(&sCb[(wave * 16 + lrow) * 72 + ks * 32 + lk8]);
#pragma unroll
        for (int t = 0; t < 4; ++t) {
            bf16x8 bb = *(const bf16x8*)(&sP[(t * 16 + lrow) * 72 + ks * 32 + lk8]);
            acc[t] = __builtin_amdgcn_mfma_f32_16x16x32_bf16(a, bb, acc[t], 0, 0, 0);
        }
    }
    __builtin_amdgcn_s_setprio(0);
#pragma unroll
    for (int t = 0; t < 4; ++t) {
#pragma unroll
        for (int r = 0; r < 4; ++r) {
            int l = wave * 16 + (lane >> 4) * 4 + r;
            int p = t * 16 + lrow;
            size_t idx = (size_t)(row0 + l) * D_INNERn + h * HEAD_DIMn + p;
            y[idx] = f2b(b2f(y[idx]) + acc[t][r] * se[l]);
        }
    }
}

// ---------------------------------------------------------------------------
// y_bf = bf16( RMSNorm(y * silu(z)) * norm_weight )   (y input bf16)
// ---------------------------------------------------------------------------
__global__ __launch_bounds__(256) void gate_norm_kernel(
    const unsigned short* __restrict__ y, const bf16* __restrict__ zb,
    const float* __restrict__ nw, bf16* __restrict__ y_bf) {
    const int row = blockIdx.x;
    const int tid = threadIdx.x;
    const size_t base = (size_t)row * D_INNERn + tid * 4;
    ushort4 yu = *(const ushort4*)(y + base);
    ushort4 zu = *(const ushort4*)((const unsigned short*)zb + base);
    float v0 = b2f(yu.x) * silu_f(b2f(zu.x));
    float v1 = b2f(yu.y) * silu_f(b2f(zu.y));
    float v2 = b2f(yu.z) * silu_f(b2f(zu.z));
    float v3 = b2f(yu.w) * silu_f(b2f(zu.w));
    float ss = v0 * v0 + v1 * v1 + v2 * v2 + v3 * v3;
#pragma unroll
    for (int o = 32; o > 0; o >>= 1) ss += __shfl_xor(ss, o);
    __shared__ float sred[4];
    if ((tid & 63) == 0) sred[tid >> 6] = ss;
    __syncthreads();
    float total = sred[0] + sred[1] + sred[2] + sred[3];
    float scale = rsqrtf(total * (1.0f / D_INNERn) + 1e-5f);
    float4 wv = *(const float4*)(nw + tid * 4);
    ushort4 o4;
    o4.x = f2b(v0 * scale * wv.x);
    o4.y = f2b(v1 * scale * wv.y);
    o4.z = f2b(v2 * scale * wv.z);
    o4.w = f2b(v3 * scale * wv.w);
    *(ushort4*)((unsigned short*)y_bf + base) = o4;
}

// ---------------------------------------------------------------------------
extern "C" void kernel_launch(void* const* d_in, const int* in_sizes, int n_in,
                              void* d_out, int out_size, void* d_ws, size_t ws_size,
                              hipStream_t stream) {
    (void)in_sizes; (void)n_in; (void)out_size; (void)ws_size;
    const float* x       = (const float*)d_in[0];
    const float* W_in    = (const float*)d_in[1];
    const float* ckx     = (const float*)d_in[2];
    const float* cbx     = (const float*)d_in[3];
    const float* ckz     = (const float*)d_in[4];
    const float* cbz     = (const float*)d_in[5];
    const float* W_xdbl  = (const float*)d_in[6];
    const float* dt_bias = (const float*)d_in[7];
    const float* A_log   = (const float*)d_in[8];
    const float* Dvec    = (const float*)d_in[9];
    const float* nw      = (const float*)d_in[10];
    const float* W_out   = (const float*)d_in[11];
    float* out = (float*)d_out;   // f32 output (round-6 verified)
    char* w = (char*)d_ws;

    // Workspace layout (bytes), total 212,877,312 — proven size.
    bf16*  xz     = (bf16*)(w);               // [BL][2048] bf16 = 67,108,864
    unsigned short* y = (unsigned short*)(w); // alias: bf16 [BL][1024] (xz dead)
    bf16*  xi     = (bf16*)(w + 67108864);    // [BL][1024] bf16 = 33,554,432
    bf16*  zb     = (bf16*)(w + 100663296);   // [BL][1024] bf16 = 33,554,432
    char*  Sreg   = w + 134217728;            // 67,108,864 region, multi-use:
    unsigned short* S = (unsigned short*)Sreg;//   [4096][4096] bf16 = 33.5M (SSD)
    bf16*  x_bf   = (bf16*)Sreg;              //   prologue: [BL][512] bf16 = 16.8M
    bf16*  W_in_T = (bf16*)(Sreg + 16777216); //   prologue: [2048][512] bf16 = 2.1M
    bf16*  W_xd_T = (bf16*)(Sreg + 18874368); //   prologue: [144][1024] bf16 = 0.3M
    bf16*  y_bf   = (bf16*)Sreg;              //   epilogue: [BL][1024] bf16 = 33.5M
    bf16*  W_o_T  = (bf16*)(Sreg + 33554432); //   epilogue: [512][1024] bf16 = 1.0M
    unsigned short* xdbl = (unsigned short*)(w + 201326592);  // [BL][144] bf16 = 4.7M
    float* acum   = (float*)(w + 211812352);  // [4096][64] f32  =  1,048,576
    float* rchunk = (float*)(w + 212860928);  // [4096] f32      =     16,384

    // 0. prologue converts (into S region — dead until ssd_chunk)
    cvt_f32_bf16<<<BL * D_MODELn / 1024, 256, 0, stream>>>(x, x_bf);
    transpose_cvt<<<dim3(2048 / 32, 512 / 32), 256, 0, stream>>>(W_in, W_in_T, 512, 2048);
    transpose_cvt<<<dim3(5, 1024 / 32), 256, 0, stream>>>(W_xdbl, W_xd_T, 1024, 144);
    // 1. xz = x @ W_in  (MFMA wide 128x256, BK=64, XCD swizzle), store bf16
    gemm_mfma_wide<bf16><<<dim3(2048 / 256, BL / 128), 512, 0, stream>>>(
        x_bf, W_in_T, xz, BL, 2048, D_MODELn);
    // 2. conv + silu -> xi, zb (register-rolling 16-row tile)
    conv_silu_kernel<<<BL / 16, 256, 0, stream>>>(xz, ckx, cbx, ckz, cbz, xi, zb);
    // 3. x_dbl = xi @ W_xdbl  (MFMA 128², r12 form), bf16 out
    gemm_mfma<bf16><<<dim3(2, BL / 128), 256, 0, stream>>>(
        xi, W_xd_T, (bf16*)xdbl, BL, XDBL_N, D_INNERn);
    // 4+5. SSD per-chunk (MFMA, dt fused, setprio): Y_diag + states
    ssd_chunk_mfma<<<B_SZn * NCHUNK * N_HEADSn, 256, 0, stream>>>(
        xdbl, xi, dt_bias, A_log, Dvec, y, S, acum, rchunk);
    // 6. inter-chunk scan (in place, bf16)
    chunk_scan_kernel<<<B_SZn * N_HEADSn * 2048 / 256, 256, 0, stream>>>(S, rchunk);
    // 7. Y_off accumulate (MFMA, bf16 RMW, setprio)
    yoff_mfma<<<B_SZn * NCHUNK * N_HEADSn, 256, 0, stream>>>(xdbl, S, acum, y);
    // 8. epilogue: W_out^T (S dead after yoff), gate+norm -> y_bf
    transpose_cvt<<<dim3(512 / 32, 1024 / 32), 256, 0, stream>>>(W_out, W_o_T, 1024, 512);
    gate_norm_kernel<<<BL, 256, 0, stream>>>(y, zb, nw, y_bf);
    // 9. out = y @ W_out  (MFMA 128², r12 form), store f32 to d_out
    gemm_mfma<float><<<dim3(512 / 128, BL / 128), 256, 0, stream>>>(
        y_bf, W_o_T, out, BL, D_MODELn, D_INNERn);
}

// Round 18
// 237.034 us; speedup vs baseline: 1.0352x; 1.0259x over previous
//
#include <hip/hip_runtime.h>
#include <hip/hip_bf16.h>
#include <cstdint>

#define B_SZn 4
#define SEQ_L 4096
#define D_MODELn 512
#define D_INNERn 1024
#define N_HEADSn 16
#define HEAD_DIMn 64
#define D_STATEn 64
#define CHUNKn 64
#define NCHUNK (SEQ_L / CHUNKn)          // 64
#define BL (B_SZn * SEQ_L)               // 16384
#define XDBL_N (N_HEADSn + 2 * D_STATEn) // 144

typedef __hip_bfloat16 bf16;
typedef __bf16 bf16x8 __attribute__((ext_vector_type(8)));
typedef float f32x4 __attribute__((ext_vector_type(4)));

__device__ __forceinline__ float silu_f(float v) {
    return v / (1.0f + expf(-v));
}
__device__ __forceinline__ float b2f(unsigned short u) {
    return __uint_as_float((unsigned)u << 16);
}
__device__ __forceinline__ unsigned short f2b(float f) {
    bf16 h = __float2bfloat16(f);
    return *(unsigned short*)&h;
}
__device__ __forceinline__ void stf(float* p, float v) { *p = v; }
__device__ __forceinline__ void stf(bf16* p, float v) { *p = __float2bfloat16(v); }

__device__ __forceinline__ float4 us4_to_f4(ushort4 u) {
    float4 f;
    f.x = b2f(u.x); f.y = b2f(u.y); f.z = b2f(u.z); f.w = b2f(u.w);
    return f;
}

// async global->LDS 16B copy (m97/m193-proven pattern).
__device__ __forceinline__ void async_copy16(void* lds, const void* g) {
    __builtin_amdgcn_global_load_lds(
        (const __attribute__((address_space(1))) unsigned int*)g,
        (__attribute__((address_space(3))) unsigned int*)lds, 16, 0, 0);
}

// ---------------------------------------------------------------------------
// x (f32) -> bf16 elementwise convert
// ---------------------------------------------------------------------------
__global__ __launch_bounds__(256) void cvt_f32_bf16(
    const float* __restrict__ in, bf16* __restrict__ out) {
    const int idx = blockIdx.x * 256 + threadIdx.x;
    float4 v = *(const float4*)(in + (size_t)idx * 4);
    ushort4 o;
    o.x = f2b(v.x); o.y = f2b(v.y); o.z = f2b(v.z); o.w = f2b(v.w);
    *(ushort4*)((unsigned short*)out + (size_t)idx * 4) = o;
}

// ---------------------------------------------------------------------------
// Transpose + convert: out[c][r] = bf16(in[r][c]).  in [R][C] f32.
// ---------------------------------------------------------------------------
__global__ __launch_bounds__(256) void transpose_cvt(
    const float* __restrict__ in, bf16* __restrict__ out, int R, int C) {
    __shared__ float t[32][33];
    const int bc = blockIdx.x * 32, br = blockIdx.y * 32;
    const int tx = threadIdx.x & 31, ty = threadIdx.x >> 5;  // ty 0..7
#pragma unroll
    for (int i = ty; i < 32; i += 8) {
        int r = br + i, c = bc + tx;
        t[i][tx] = (r < R && c < C) ? in[(size_t)r * C + c] : 0.f;
    }
    __syncthreads();
#pragma unroll
    for (int i = ty; i < 32; i += 8) {
        int c = bc + i, r = br + tx;
        if (c < C && r < R) out[(size_t)c * R + r] = __float2bfloat16(t[tx][i]);
    }
}

// ---------------------------------------------------------------------------
// bf16 MFMA GEMM (r12/r14-proven best): C[M,N] = A[M,K] @ Bt[N,K]^T.
// 128x128 tile, BK=64 as two 32-wide half-subtiles, single-buffered
// global_load_lds staging, XCD-aware block swizzle (T1).  4 waves, 32KB LDS.
// ---------------------------------------------------------------------------
template <typename TO>
__global__ __launch_bounds__(256) void gemm_mfma(
    const bf16* __restrict__ A, const bf16* __restrict__ Bt,
    TO* __restrict__ C, int M, int N, int K) {
    __shared__ __align__(16) unsigned short Al[2][128 * 32];
    __shared__ __align__(16) unsigned short Bl[2][128 * 32];
    const int tid = threadIdx.x;
    const int wave = tid >> 6, lane = tid & 63;
    const int wm = (wave >> 1) * 64, wn = (wave & 1) * 64;
    int lin = blockIdx.y * gridDim.x + blockIdx.x;
    const int nwg = gridDim.x * gridDim.y;
    if ((nwg & 7) == 0) lin = (lin & 7) * (nwg >> 3) + (lin >> 3);
    const int bm = (lin / gridDim.x) * 128, bn = (lin % gridDim.x) * 128;
    f32x4 acc[4][4];
#pragma unroll
    for (int m = 0; m < 4; ++m)
#pragma unroll
        for (int n = 0; n < 4; ++n) acc[m][n] = (f32x4)(0.f);

    const int lrow = lane & 15, lk8 = (lane >> 4) * 8;
    const int srow = tid >> 2, sc8 = (tid & 3) * 8;
    for (int k0 = 0; k0 < K; k0 += 64) {
#pragma unroll
        for (int h = 0; h < 2; ++h) {
            const int kh = k0 + h * 32;
            async_copy16((char*)&Al[h][0] + (size_t)(wave * 64) * 16,
                         A + (size_t)(bm + srow) * K + kh + sc8);
            async_copy16((char*)&Al[h][0] + (size_t)(256 + wave * 64) * 16,
                         A + (size_t)(bm + 64 + srow) * K + kh + sc8);
            async_copy16((char*)&Bl[h][0] + (size_t)(wave * 64) * 16,
                         Bt + (size_t)(bn + srow) * K + kh + sc8);
            async_copy16((char*)&Bl[h][0] + (size_t)(256 + wave * 64) * 16,
                         Bt + (size_t)(bn + 64 + srow) * K + kh + sc8);
        }
        __syncthreads();
#pragma unroll
        for (int h = 0; h < 2; ++h) {
            bf16x8 af[4], bfr[4];
#pragma unroll
            for (int m = 0; m < 4; ++m)
                af[m] = *(const bf16x8*)(&Al[h][(wm + m * 16 + lrow) * 32 + lk8]);
#pragma unroll
            for (int n = 0; n < 4; ++n)
                bfr[n] = *(const bf16x8*)(&Bl[h][(wn + n * 16 + lrow) * 32 + lk8]);
#pragma unroll
            for (int m = 0; m < 4; ++m)
#pragma unroll
                for (int n = 0; n < 4; ++n)
                    acc[m][n] = __builtin_amdgcn_mfma_f32_16x16x32_bf16(
                        af[m], bfr[n], acc[m][n], 0, 0, 0);
        }
        __syncthreads();
    }
#pragma unroll
    for (int m = 0; m < 4; ++m) {
#pragma unroll
        for (int n = 0; n < 4; ++n) {
#pragma unroll
            for (int r = 0; r < 4; ++r) {
                int row = bm + wm + m * 16 + (lane >> 4) * 4 + r;
                int col = bn + wn + n * 16 + (lane & 15);
                if (row < M && col < N)
                    stf(&C[(size_t)row * N + col], acc[m][n][r]);
            }
        }
    }
}

// ---------------------------------------------------------------------------
// Wide-N variant (r14-proven for GEMM1): 128x256 tile, 8 waves (2Mx4N),
// 512 threads, BK=64 half-split, 48KB LDS (3 blocks/CU).
// ---------------------------------------------------------------------------
template <typename TO>
__global__ __launch_bounds__(512) void gemm_mfma_wide(
    const bf16* __restrict__ A, const bf16* __restrict__ Bt,
    TO* __restrict__ C, int M, int N, int K) {
    __shared__ __align__(16) unsigned short Al[2][128 * 32];
    __shared__ __align__(16) unsigned short Bl[2][256 * 32];
    const int tid = threadIdx.x;
    const int wave = tid >> 6, lane = tid & 63;
    const int wm = (wave >> 2) * 64, wn = (wave & 3) * 64;
    int lin = blockIdx.y * gridDim.x + blockIdx.x;
    const int nwg = gridDim.x * gridDim.y;
    if ((nwg & 7) == 0) lin = (lin & 7) * (nwg >> 3) + (lin >> 3);
    const int bm = (lin / gridDim.x) * 128, bn = (lin % gridDim.x) * 256;
    f32x4 acc[4][4];
#pragma unroll
    for (int m = 0; m < 4; ++m)
#pragma unroll
        for (int n = 0; n < 4; ++n) acc[m][n] = (f32x4)(0.f);

    const int lrow = lane & 15, lk8 = (lane >> 4) * 8;
    const int srow = tid >> 2, sc8 = (tid & 3) * 8;  // 512 thr: A 1 seg, B 2 segs
    for (int k0 = 0; k0 < K; k0 += 64) {
#pragma unroll
        for (int h = 0; h < 2; ++h) {
            const int kh = k0 + h * 32;
            async_copy16((char*)&Al[h][0] + (size_t)(wave * 64) * 16,
                         A + (size_t)(bm + srow) * K + kh + sc8);
            async_copy16((char*)&Bl[h][0] + (size_t)(wave * 64) * 16,
                         Bt + (size_t)(bn + srow) * K + kh + sc8);
            async_copy16((char*)&Bl[h][0] + (size_t)(512 + wave * 64) * 16,
                         Bt + (size_t)(bn + 128 + srow) * K + kh + sc8);
        }
        __syncthreads();
#pragma unroll
        for (int h = 0; h < 2; ++h) {
            bf16x8 af[4], bfr[4];
#pragma unroll
            for (int m = 0; m < 4; ++m)
                af[m] = *(const bf16x8*)(&Al[h][(wm + m * 16 + lrow) * 32 + lk8]);
#pragma unroll
            for (int n = 0; n < 4; ++n)
                bfr[n] = *(const bf16x8*)(&Bl[h][(wn + n * 16 + lrow) * 32 + lk8]);
#pragma unroll
            for (int m = 0; m < 4; ++m)
#pragma unroll
                for (int n = 0; n < 4; ++n)
                    acc[m][n] = __builtin_amdgcn_mfma_f32_16x16x32_bf16(
                        af[m], bfr[n], acc[m][n], 0, 0, 0);
        }
        __syncthreads();
    }
#pragma unroll
    for (int m = 0; m < 4; ++m) {
#pragma unroll
        for (int n = 0; n < 4; ++n) {
#pragma unroll
            for (int r = 0; r < 4; ++r) {
                int row = bm + wm + m * 16 + (lane >> 4) * 4 + r;
                int col = bn + wn + n * 16 + (lane & 15);
                if (row < M && col < N)
                    stf(&C[(size_t)row * N + col], acc[m][n][r]);
            }
        }
    }
}

// ---------------------------------------------------------------------------
// Depthwise conv + bias + silu, register-rolling over an 8-row L-tile
// (r14-proven best config).
// ---------------------------------------------------------------------------
__global__ __launch_bounds__(256) void conv_silu_kernel(
    const bf16* __restrict__ xz,
    const float* __restrict__ kx, const float* __restrict__ bx,
    const float* __restrict__ kz, const float* __restrict__ bz,
    bf16* __restrict__ xi, bf16* __restrict__ zo) {
    const int tid = threadIdx.x;
    const int d4 = tid * 4;                    // 0..1020
    const int blk = blockIdx.x;                // BL/8 blocks
    const int l0 = (blk * 8) & (SEQ_L - 1);
    const int b = (blk * 8) >> 12;             // /SEQ_L
    const unsigned short* base = (const unsigned short*)xz +
                                 ((size_t)b * SEQ_L) * (2 * D_INNERn);
    float4 wx[4], wz[4];
#pragma unroll
    for (int k = 0; k < 4; ++k) {
        wx[k] = *(const float4*)(kx + k * D_INNERn + d4);
        wz[k] = *(const float4*)(kz + k * D_INNERn + d4);
    }
    const float4 bxv = *(const float4*)(bx + d4);
    const float4 bzv = *(const float4*)(bz + d4);
    float4 vx[4], vz[4];
#pragma unroll
    for (int j = 0; j < 3; ++j) {
        int l = l0 - 1 + j;
        if (l >= 0) {
            const unsigned short* row = base + (size_t)l * (2 * D_INNERn);
            vx[j] = us4_to_f4(*(const ushort4*)(row + d4));
            vz[j] = us4_to_f4(*(const ushort4*)(row + D_INNERn + d4));
        } else {
            vx[j] = make_float4(0.f, 0.f, 0.f, 0.f);
            vz[j] = make_float4(0.f, 0.f, 0.f, 0.f);
        }
    }
    unsigned short* xout = (unsigned short*)xi;
    unsigned short* zout = (unsigned short*)zo;
#pragma unroll
    for (int j = 0; j < 8; ++j) {
        const int lread = l0 + 2 + j;
        if (lread < SEQ_L) {
            const unsigned short* row = base + (size_t)lread * (2 * D_INNERn);
            vx[3] = us4_to_f4(*(const ushort4*)(row + d4));
            vz[3] = us4_to_f4(*(const ushort4*)(row + D_INNERn + d4));
        } else {
            vx[3] = make_float4(0.f, 0.f, 0.f, 0.f);
            vz[3] = make_float4(0.f, 0.f, 0.f, 0.f);
        }
        float4 ax = bxv, az = bzv;
#pragma unroll
        for (int k = 0; k < 4; ++k) {
            ax.x += vx[k].x * wx[k].x; ax.y += vx[k].y * wx[k].y;
            ax.z += vx[k].z * wx[k].z; ax.w += vx[k].w * wx[k].w;
            az.x += vz[k].x * wz[k].x; az.y += vz[k].y * wz[k].y;
            az.z += vz[k].z * wz[k].z; az.w += vz[k].w * wz[k].w;
        }
        ushort4 ox, oz;
        ox.x = f2b(silu_f(ax.x)); ox.y = f2b(silu_f(ax.y));
        ox.z = f2b(silu_f(ax.z)); ox.w = f2b(silu_f(ax.w));
        oz.x = f2b(silu_f(az.x)); oz.y = f2b(silu_f(az.y));
        oz.z = f2b(silu_f(az.z)); oz.w = f2b(silu_f(az.w));
        const size_t obase = ((size_t)b * SEQ_L + l0 + j) * D_INNERn + d4;
        *(ushort4*)(xout + obase) = ox;
        *(ushort4*)(zout + obase) = oz;
        vx[0] = vx[1]; vx[1] = vx[2]; vx[2] = vx[3];
        vz[0] = vz[1]; vz[1] = vz[2]; vz[2] = vz[3];
    }
}

// ---------------------------------------------------------------------------
// MFMA SSD chunk: per (b,c,h) block, 4 waves.  dt=softplus fused; setprio.
// LDS cut 46KB -> 37.7KB by aliasing sWB onto sCb (dead after MFMA1 +
// barrier) -> 4 blocks/CU instead of 3.
// ---------------------------------------------------------------------------
__global__ __launch_bounds__(256) void ssd_chunk_mfma(
    const unsigned short* __restrict__ xdbl, const bf16* __restrict__ xi,
    const float* __restrict__ dt_bias, const float* __restrict__ A_log,
    const float* __restrict__ Dvec,
    unsigned short* __restrict__ y, unsigned short* __restrict__ S,
    float* __restrict__ acum_g, float* __restrict__ rchunk) {
    __shared__ __align__(16) unsigned short sBb[64 * 72];  // B[s][n]
    __shared__ __align__(16) unsigned short sCb[64 * 72];  // C[l][n]; reused as
                                                           // (w·B)^T[n][s] after MFMA1
    __shared__ __align__(16) unsigned short sXT[64 * 72];  // X^T[p][s]
    __shared__ __align__(16) unsigned short sGb[64 * 72];  // G[l][s]
    __shared__ float sdtp[64], sacum[64], sw[64];
    unsigned short* sWB = sCb;           // alias: sCb dead after MFMA1+barrier
    const int bid = blockIdx.x;          // ((b*64 + c)*16 + h)
    const int h = bid & 15;
    const int bc = bid >> 4;
    const int c = bc & (NCHUNK - 1);
    const int b = bc >> 6;
    const int tid = threadIdx.x;
    const int wave = tid >> 6, lane = tid & 63;
    const int lrow = lane & 15, lk8 = (lane >> 4) * 8;
    const int row0 = b * SEQ_L + c * CHUNKn;
    const float Ah = -expf(A_log[h]);
    const float Dh = Dvec[h];

    if (tid < 64) {  // fused dt = softplus(xdbl[..,h] + dt_bias[h])
        float v = b2f(xdbl[(size_t)(row0 + tid) * XDBL_N + h]) + dt_bias[h];
        sdtp[tid] = (v > 20.f) ? v : log1pf(expf(v));
    }
    const unsigned short* xius = (const unsigned short*)xi;
#pragma unroll
    for (int it = 0; it < 16; ++it) {
        int e = tid + it * 256;
        int s = e >> 6, n = e & 63;
        const unsigned short* xr = xdbl + (size_t)(row0 + s) * XDBL_N + N_HEADSn;
        sBb[s * 72 + n] = xr[n];
        sCb[s * 72 + n] = xr[D_STATEn + n];
        sXT[n * 72 + s] = xius[(size_t)(row0 + s) * D_INNERn + h * HEAD_DIMn + n];
    }
    __syncthreads();
    if (wave == 0) {
        float v = Ah * sdtp[lane];
#pragma unroll
        for (int o = 1; o < 64; o <<= 1) {
            float t = __shfl_up(v, o);
            if (lane >= o) v += t;
        }
        sacum[lane] = v;
        float last = __shfl(v, 63);
        sw[lane] = expf(last - v) * sdtp[lane];
        acum_g[(size_t)bid * 64 + lane] = v;
        if (lane == 63) rchunk[bid] = expf(v);
    }
    // MFMA1: Graw = C·B^T   (last read of sCb as C-operand)
    f32x4 acc1[4];
#pragma unroll
    for (int t = 0; t < 4; ++t) acc1[t] = (f32x4)(0.f);
    __builtin_amdgcn_s_setprio(1);
#pragma unroll
    for (int ks = 0; ks < 2; ++ks) {
        bf16x8 a = *(const bf16x8*)(&sCb[(wave * 16 + lrow) * 72 + ks * 32 + lk8]);
#pragma unroll
        for (int t = 0; t < 4; ++t) {
            bf16x8 bb = *(const bf16x8*)(&sBb[(t * 16 + lrow) * 72 + ks * 32 + lk8]);
            acc1[t] = __builtin_amdgcn_mfma_f32_16x16x32_bf16(a, bb, acc1[t], 0, 0, 0);
        }
    }
    __builtin_amdgcn_s_setprio(0);
    __syncthreads();   // after this barrier sCb storage is free -> sWB
#pragma unroll
    for (int t = 0; t < 4; ++t) {
#pragma unroll
        for (int r = 0; r < 4; ++r) {
            int l = wave * 16 + (lane >> 4) * 4 + r;
            int s = t * 16 + lrow;
            float val = 0.f;
            if (l >= s) val = acc1[t][r] * expf(sacum[l] - sacum[s]) * sdtp[s];
            sGb[l * 72 + s] = f2b(val);
        }
    }
#pragma unroll
    for (int it = 0; it < 16; ++it) {
        int e = tid + it * 256;
        int s = e >> 6, n = e & 63;
        sWB[n * 72 + s] = f2b(sw[s] * b2f(sBb[s * 72 + n]));
    }
    __syncthreads();
    f32x4 acc2[4], acc3[4];
#pragma unroll
    for (int t = 0; t < 4; ++t) { acc2[t] = (f32x4)(0.f); acc3[t] = (f32x4)(0.f); }
    __builtin_amdgcn_s_setprio(1);
#pragma unroll
    for (int ks = 0; ks < 2; ++ks) {
        bf16x8 a2 = *(const bf16x8*)(&sGb[(wave * 16 + lrow) * 72 + ks * 32 + lk8]);
        bf16x8 a3 = *(const bf16x8*)(&sXT[(wave * 16 + lrow) * 72 + ks * 32 + lk8]);
#pragma unroll
        for (int t = 0; t < 4; ++t) {
            bf16x8 b2v = *(const bf16x8*)(&sXT[(t * 16 + lrow) * 72 + ks * 32 + lk8]);
            bf16x8 b3v = *(const bf16x8*)(&sWB[(t * 16 + lrow) * 72 + ks * 32 + lk8]);
            acc2[t] = __builtin_amdgcn_mfma_f32_16x16x32_bf16(a2, b2v, acc2[t], 0, 0, 0);
            acc3[t] = __builtin_amdgcn_mfma_f32_16x16x32_bf16(a3, b3v, acc3[t], 0, 0, 0);
        }
    }
    __builtin_amdgcn_s_setprio(0);
#pragma unroll
    for (int t = 0; t < 4; ++t) {
#pragma unroll
        for (int r = 0; r < 4; ++r) {
            int rr = wave * 16 + (lane >> 4) * 4 + r;
            int cc = t * 16 + lrow;
            float xv = b2f(sXT[cc * 72 + rr]);
            y[(size_t)(row0 + rr) * D_INNERn + h * HEAD_DIMn + cc] =
                f2b(acc2[t][r] + Dh * xv);
            S[(size_t)bid * 4096 + rr * 64 + cc] = f2b(acc3[t][r]);
        }
    }
}

// ---------------------------------------------------------------------------
// Inter-chunk scan (bf16 S, f32 running state): S[c] <- state ENTERING c.
// ---------------------------------------------------------------------------
__global__ __launch_bounds__(256) void chunk_scan_kernel(
    unsigned short* __restrict__ S, const float* __restrict__ rchunk) {
    const int idx = blockIdx.x * 256 + threadIdx.x;  // BH * 2048
    const int pn2 = (idx & 2047) * 2;
    const int bh = idx >> 11;
    const int h = bh & 15;
    const int b = bh >> 4;
    float P0 = 0.f, P1 = 0.f;
    for (int c = 0; c < NCHUNK; ++c) {
        int bid = (b * NCHUNK + c) * N_HEADSn + h;
        size_t off = (size_t)bid * 4096 + pn2;
        unsigned int v = *(unsigned int*)(S + off);
        float s0 = b2f((unsigned short)(v & 0xffff));
        float s1 = b2f((unsigned short)(v >> 16));
        *(unsigned int*)(S + off) =
            (unsigned int)f2b(P0) | ((unsigned int)f2b(P1) << 16);
        float rc = rchunk[bid];
        P0 = rc * P0 + s0;
        P1 = rc * P1 + s1;
    }
}

// ---------------------------------------------------------------------------
// MFMA Y_off: y[l][p] += exp(acum[l]) * sum_n C[l][n] * P[p][n]  (all bf16)
// ---------------------------------------------------------------------------
__global__ __launch_bounds__(256) void yoff_mfma(
    const unsigned short* __restrict__ xdbl, const unsigned short* __restrict__ S,
    const float* __restrict__ acum_g, unsigned short* __restrict__ y) {
    __shared__ __align__(16) unsigned short sCb[64 * 72];
    __shared__ __align__(16) unsigned short sP[64 * 72];
    __shared__ float se[64];
    const int bid = blockIdx.x;
    const int h = bid & 15;
    const int bc = bid >> 4;
    const int c = bc & (NCHUNK - 1);
    const int b = bc >> 6;
    const int tid = threadIdx.x;
    const int wave = tid >> 6, lane = tid & 63;
    const int lrow = lane & 15, lk8 = (lane >> 4) * 8;
    const int row0 = b * SEQ_L + c * CHUNKn;
    if (tid < 64) se[tid] = expf(acum_g[(size_t)bid * 64 + tid]);
#pragma unroll
    for (int it = 0; it < 16; ++it) {
        int e = tid + it * 256;
        int r = e >> 6, n = e & 63;
        sCb[r * 72 + n] = xdbl[(size_t)(row0 + r) * XDBL_N + N_HEADSn + D_STATEn + n];
        sP[r * 72 + n] = S[(size_t)bid * 4096 + e];
    }
    __syncthreads();
    f32x4 acc[4];
#pragma unroll
    for (int t = 0; t < 4; ++t) acc[t] = (f32x4)(0.f);
    __builtin_amdgcn_s_setprio(1);
#pragma unroll
    for (int ks = 0; ks < 2; ++ks) {
        bf16x8 a = *(const bf16x8*)(&sCb[(wave * 16 + lrow) * 72 + ks * 32 + lk8]);
#pragma unroll
        for (int t = 0; t < 4; ++t) {
            bf16x8 bb = *(const bf16x8*)(&sP[(t * 16 + lrow) * 72 + ks * 32 + lk8]);
            acc[t] = __builtin_amdgcn_mfma_f32_16x16x32_bf16(a, bb, acc[t], 0, 0, 0);
        }
    }
    __builtin_amdgcn_s_setprio(0);
#pragma unroll
    for (int t = 0; t < 4; ++t) {
#pragma unroll
        for (int r = 0; r < 4; ++r) {
            int l = wave * 16 + (lane >> 4) * 4 + r;
            int p = t * 16 + lrow;
            size_t idx = (size_t)(row0 + l) * D_INNERn + h * HEAD_DIMn + p;
            y[idx] = f2b(b2f(y[idx]) + acc[t][r] * se[l]);
        }
    }
}

// ---------------------------------------------------------------------------
// y_bf = bf16( RMSNorm(y * silu(z)) * norm_weight )   (y input bf16)
// ---------------------------------------------------------------------------
__global__ __launch_bounds__(256) void gate_norm_kernel(
    const unsigned short* __restrict__ y, const bf16* __restrict__ zb,
    const float* __restrict__ nw, bf16* __restrict__ y_bf) {
    const int row = blockIdx.x;
    const int tid = threadIdx.x;
    const size_t base = (size_t)row * D_INNERn + tid * 4;
    ushort4 yu = *(const ushort4*)(y + base);
    ushort4 zu = *(const ushort4*)((const unsigned short*)zb + base);
    float v0 = b2f(yu.x) * silu_f(b2f(zu.x));
    float v1 = b2f(yu.y) * silu_f(b2f(zu.y));
    float v2 = b2f(yu.z) * silu_f(b2f(zu.z));
    float v3 = b2f(yu.w) * silu_f(b2f(zu.w));
    float ss = v0 * v0 + v1 * v1 + v2 * v2 + v3 * v3;
#pragma unroll
    for (int o = 32; o > 0; o >>= 1) ss += __shfl_xor(ss, o);
    __shared__ float sred[4];
    if ((tid & 63) == 0) sred[tid >> 6] = ss;
    __syncthreads();
    float total = sred[0] + sred[1] + sred[2] + sred[3];
    float scale = rsqrtf(total * (1.0f / D_INNERn) + 1e-5f);
    float4 wv = *(const float4*)(nw + tid * 4);
    ushort4 o4;
    o4.x = f2b(v0 * scale * wv.x);
    o4.y = f2b(v1 * scale * wv.y);
    o4.z = f2b(v2 * scale * wv.z);
    o4.w = f2b(v3 * scale * wv.w);
    *(ushort4*)((unsigned short*)y_bf + base) = o4;
}

// ---------------------------------------------------------------------------
extern "C" void kernel_launch(void* const* d_in, const int* in_sizes, int n_in,
                              void* d_out, int out_size, void* d_ws, size_t ws_size,
                              hipStream_t stream) {
    (void)in_sizes; (void)n_in; (void)out_size; (void)ws_size;
    const float* x       = (const float*)d_in[0];
    const float* W_in    = (const float*)d_in[1];
    const float* ckx     = (const float*)d_in[2];
    const float* cbx     = (const float*)d_in[3];
    const float* ckz     = (const float*)d_in[4];
    const float* cbz     = (const float*)d_in[5];
    const float* W_xdbl  = (const float*)d_in[6];
    const float* dt_bias = (const float*)d_in[7];
    const float* A_log   = (const float*)d_in[8];
    const float* Dvec    = (const float*)d_in[9];
    const float* nw      = (const float*)d_in[10];
    const float* W_out   = (const float*)d_in[11];
    float* out = (float*)d_out;   // f32 output (round-6 verified)
    char* w = (char*)d_ws;

    // Workspace layout (bytes), total 212,877,312 — proven size.
    bf16*  xz     = (bf16*)(w);               // [BL][2048] bf16 = 67,108,864
    unsigned short* y = (unsigned short*)(w); // alias: bf16 [BL][1024] (xz dead)
    bf16*  xi     = (bf16*)(w + 67108864);    // [BL][1024] bf16 = 33,554,432
    bf16*  zb     = (bf16*)(w + 100663296);   // [BL][1024] bf16 = 33,554,432
    char*  Sreg   = w + 134217728;            // 67,108,864 region, multi-use:
    unsigned short* S = (unsigned short*)Sreg;//   [4096][4096] bf16 = 33.5M (SSD)
    bf16*  x_bf   = (bf16*)Sreg;              //   prologue: [BL][512] bf16 = 16.8M
    bf16*  W_in_T = (bf16*)(Sreg + 16777216); //   prologue: [2048][512] bf16 = 2.1M
    bf16*  W_xd_T = (bf16*)(Sreg + 18874368); //   prologue: [144][1024] bf16 = 0.3M
    bf16*  y_bf   = (bf16*)Sreg;              //   epilogue: [BL][1024] bf16 = 33.5M
    bf16*  W_o_T  = (bf16*)(Sreg + 33554432); //   epilogue: [512][1024] bf16 = 1.0M
    unsigned short* xdbl = (unsigned short*)(w + 201326592);  // [BL][144] bf16 = 4.7M
    float* acum   = (float*)(w + 211812352);  // [4096][64] f32  =  1,048,576
    float* rchunk = (float*)(w + 212860928);  // [4096] f32      =     16,384

    // 0. prologue converts (into S region — dead until ssd_chunk)
    cvt_f32_bf16<<<BL * D_MODELn / 1024, 256, 0, stream>>>(x, x_bf);
    transpose_cvt<<<dim3(2048 / 32, 512 / 32), 256, 0, stream>>>(W_in, W_in_T, 512, 2048);
    transpose_cvt<<<dim3(5, 1024 / 32), 256, 0, stream>>>(W_xdbl, W_xd_T, 1024, 144);
    // 1. xz = x @ W_in  (MFMA wide 128x256, BK=64, XCD swizzle), store bf16
    gemm_mfma_wide<bf16><<<dim3(2048 / 256, BL / 128), 512, 0, stream>>>(
        x_bf, W_in_T, xz, BL, 2048, D_MODELn);
    // 2. conv + silu -> xi, zb (register-rolling 8-row tile, r14-proven)
    conv_silu_kernel<<<BL / 8, 256, 0, stream>>>(xz, ckx, cbx, ckz, cbz, xi, zb);
    // 3. x_dbl = xi @ W_xdbl  (MFMA 128², r12 form), bf16 out
    gemm_mfma<bf16><<<dim3(2, BL / 128), 256, 0, stream>>>(
        xi, W_xd_T, (bf16*)xdbl, BL, XDBL_N, D_INNERn);
    // 4+5. SSD per-chunk (MFMA, dt fused, setprio, 37.7KB LDS): Y_diag + states
    ssd_chunk_mfma<<<B_SZn * NCHUNK * N_HEADSn, 256, 0, stream>>>(
        xdbl, xi, dt_bias, A_log, Dvec, y, S, acum, rchunk);
    // 6. inter-chunk scan (in place, bf16)
    chunk_scan_kernel<<<B_SZn * N_HEADSn * 2048 / 256, 256, 0, stream>>>(S, rchunk);
    // 7. Y_off accumulate (MFMA, bf16 RMW, setprio)
    yoff_mfma<<<B_SZn * NCHUNK * N_HEADSn, 256, 0, stream>>>(xdbl, S, acum, y);
    // 8. epilogue: W_out^T (S dead after yoff), gate+norm -> y_bf
    transpose_cvt<<<dim3(512 / 32, 1024 / 32), 256, 0, stream>>>(W_out, W_o_T, 1024, 512);
    gate_norm_kernel<<<BL, 256, 0, stream>>>(y, zb, nw, y_bf);
    // 9. out = y @ W_out  (MFMA 128², r12 form), store f32 to d_out
    gemm_mfma<float><<<dim3(512 / 128, BL / 128), 256, 0, stream>>>(
        y_bf, W_o_T, out, BL, D_MODELn, D_INNERn);
}

// Round 19
// 231.145 us; speedup vs baseline: 1.0615x; 1.0255x over previous
//
#include <hip/hip_runtime.h>
#include <hip/hip_bf16.h>
#include <cstdint>

#define B_SZn 4
#define SEQ_L 4096
#define D_MODELn 512
#define D_INNERn 1024
#define N_HEADSn 16
#define HEAD_DIMn 64
#define D_STATEn 64
#define CHUNKn 64
#define NCHUNK (SEQ_L / CHUNKn)          // 64
#define BL (B_SZn * SEQ_L)               // 16384
#define XDBL_N (N_HEADSn + 2 * D_STATEn) // 144

typedef __hip_bfloat16 bf16;
typedef __bf16 bf16x8 __attribute__((ext_vector_type(8)));
typedef float f32x4 __attribute__((ext_vector_type(4)));

__device__ __forceinline__ float silu_f(float v) {
    return v / (1.0f + expf(-v));
}
__device__ __forceinline__ float b2f(unsigned short u) {
    return __uint_as_float((unsigned)u << 16);
}
__device__ __forceinline__ unsigned short f2b(float f) {
    bf16 h = __float2bfloat16(f);
    return *(unsigned short*)&h;
}
__device__ __forceinline__ void stf(float* p, float v) { *p = v; }
__device__ __forceinline__ void stf(bf16* p, float v) { *p = __float2bfloat16(v); }

__device__ __forceinline__ float4 us4_to_f4(ushort4 u) {
    float4 f;
    f.x = b2f(u.x); f.y = b2f(u.y); f.z = b2f(u.z); f.w = b2f(u.w);
    return f;
}

// async global->LDS 16B copy (m97/m193-proven pattern).
__device__ __forceinline__ void async_copy16(void* lds, const void* g) {
    __builtin_amdgcn_global_load_lds(
        (const __attribute__((address_space(1))) unsigned int*)g,
        (__attribute__((address_space(3))) unsigned int*)lds, 16, 0, 0);
}

// ---------------------------------------------------------------------------
// x (f32) -> bf16 elementwise convert
// ---------------------------------------------------------------------------
__global__ __launch_bounds__(256) void cvt_f32_bf16(
    const float* __restrict__ in, bf16* __restrict__ out) {
    const int idx = blockIdx.x * 256 + threadIdx.x;
    float4 v = *(const float4*)(in + (size_t)idx * 4);
    ushort4 o;
    o.x = f2b(v.x); o.y = f2b(v.y); o.z = f2b(v.z); o.w = f2b(v.w);
    *(ushort4*)((unsigned short*)out + (size_t)idx * 4) = o;
}

// ---------------------------------------------------------------------------
// Transpose + convert: out[c][r] = bf16(in[r][c]).  in [R][C] f32.
// ---------------------------------------------------------------------------
__global__ __launch_bounds__(256) void transpose_cvt(
    const float* __restrict__ in, bf16* __restrict__ out, int R, int C) {
    __shared__ float t[32][33];
    const int bc = blockIdx.x * 32, br = blockIdx.y * 32;
    const int tx = threadIdx.x & 31, ty = threadIdx.x >> 5;  // ty 0..7
#pragma unroll
    for (int i = ty; i < 32; i += 8) {
        int r = br + i, c = bc + tx;
        t[i][tx] = (r < R && c < C) ? in[(size_t)r * C + c] : 0.f;
    }
    __syncthreads();
#pragma unroll
    for (int i = ty; i < 32; i += 8) {
        int c = bc + i, r = br + tx;
        if (c < C && r < R) out[(size_t)c * R + r] = __float2bfloat16(t[tx][i]);
    }
}

// ---------------------------------------------------------------------------
// Small-M bf16 MFMA GEMM for tall-skinny shapes (GEMM2/GEMM3): 64x128 tile,
// BK=64 as two 32-wide half-subtiles, single-buffered global_load_lds,
// XCD swizzle.  4 waves (2Mx2N, each 32x64), 24KB LDS -> ~6 blocks/CU.
// M mult 64, K mult 64; N bounds-checked on store (OOB Bt rows read in-ws
// garbage that feeds only unstored columns).
// ---------------------------------------------------------------------------
template <typename TO>
__global__ __launch_bounds__(256) void gemm_mfma_m64(
    const bf16* __restrict__ A, const bf16* __restrict__ Bt,
    TO* __restrict__ C, int M, int N, int K) {
    __shared__ __align__(16) unsigned short Al[2][64 * 32];
    __shared__ __align__(16) unsigned short Bl[2][128 * 32];
    const int tid = threadIdx.x;
    const int wave = tid >> 6, lane = tid & 63;
    const int wm = (wave >> 1) * 32, wn = (wave & 1) * 64;
    int lin = blockIdx.y * gridDim.x + blockIdx.x;
    const int nwg = gridDim.x * gridDim.y;
    if ((nwg & 7) == 0) lin = (lin & 7) * (nwg >> 3) + (lin >> 3);
    const int bm = (lin / gridDim.x) * 64, bn = (lin % gridDim.x) * 128;
    f32x4 acc[2][4];
#pragma unroll
    for (int m = 0; m < 2; ++m)
#pragma unroll
        for (int n = 0; n < 4; ++n) acc[m][n] = (f32x4)(0.f);

    const int lrow = lane & 15, lk8 = (lane >> 4) * 8;
    const int srow = tid >> 2, sc8 = (tid & 3) * 8;
    for (int k0 = 0; k0 < K; k0 += 64) {
#pragma unroll
        for (int h = 0; h < 2; ++h) {
            const int kh = k0 + h * 32;
            // A half-tile 64x32 = 256 segs (1/thread)
            async_copy16((char*)&Al[h][0] + (size_t)(wave * 64) * 16,
                         A + (size_t)(bm + srow) * K + kh + sc8);
            // B half-tile 128x32 = 512 segs (2/thread)
            async_copy16((char*)&Bl[h][0] + (size_t)(wave * 64) * 16,
                         Bt + (size_t)(bn + srow) * K + kh + sc8);
            async_copy16((char*)&Bl[h][0] + (size_t)(256 + wave * 64) * 16,
                         Bt + (size_t)(bn + 64 + srow) * K + kh + sc8);
        }
        __syncthreads();
#pragma unroll
        for (int h = 0; h < 2; ++h) {
            bf16x8 af[2], bfr[4];
#pragma unroll
            for (int m = 0; m < 2; ++m)
                af[m] = *(const bf16x8*)(&Al[h][(wm + m * 16 + lrow) * 32 + lk8]);
#pragma unroll
            for (int n = 0; n < 4; ++n)
                bfr[n] = *(const bf16x8*)(&Bl[h][(wn + n * 16 + lrow) * 32 + lk8]);
#pragma unroll
            for (int m = 0; m < 2; ++m)
#pragma unroll
                for (int n = 0; n < 4; ++n)
                    acc[m][n] = __builtin_amdgcn_mfma_f32_16x16x32_bf16(
                        af[m], bfr[n], acc[m][n], 0, 0, 0);
        }
        __syncthreads();
    }
#pragma unroll
    for (int m = 0; m < 2; ++m) {
#pragma unroll
        for (int n = 0; n < 4; ++n) {
#pragma unroll
            for (int r = 0; r < 4; ++r) {
                int row = bm + wm + m * 16 + (lane >> 4) * 4 + r;
                int col = bn + wn + n * 16 + (lane & 15);
                if (row < M && col < N)
                    stf(&C[(size_t)row * N + col], acc[m][n][r]);
            }
        }
    }
}

// ---------------------------------------------------------------------------
// Wide-N variant (r14-proven for GEMM1): 128x256 tile, 8 waves (2Mx4N),
// 512 threads, BK=64 half-split, 48KB LDS (3 blocks/CU).
// ---------------------------------------------------------------------------
template <typename TO>
__global__ __launch_bounds__(512) void gemm_mfma_wide(
    const bf16* __restrict__ A, const bf16* __restrict__ Bt,
    TO* __restrict__ C, int M, int N, int K) {
    __shared__ __align__(16) unsigned short Al[2][128 * 32];
    __shared__ __align__(16) unsigned short Bl[2][256 * 32];
    const int tid = threadIdx.x;
    const int wave = tid >> 6, lane = tid & 63;
    const int wm = (wave >> 2) * 64, wn = (wave & 3) * 64;
    int lin = blockIdx.y * gridDim.x + blockIdx.x;
    const int nwg = gridDim.x * gridDim.y;
    if ((nwg & 7) == 0) lin = (lin & 7) * (nwg >> 3) + (lin >> 3);
    const int bm = (lin / gridDim.x) * 128, bn = (lin % gridDim.x) * 256;
    f32x4 acc[4][4];
#pragma unroll
    for (int m = 0; m < 4; ++m)
#pragma unroll
        for (int n = 0; n < 4; ++n) acc[m][n] = (f32x4)(0.f);

    const int lrow = lane & 15, lk8 = (lane >> 4) * 8;
    const int srow = tid >> 2, sc8 = (tid & 3) * 8;  // 512 thr: A 1 seg, B 2 segs
    for (int k0 = 0; k0 < K; k0 += 64) {
#pragma unroll
        for (int h = 0; h < 2; ++h) {
            const int kh = k0 + h * 32;
            async_copy16((char*)&Al[h][0] + (size_t)(wave * 64) * 16,
                         A + (size_t)(bm + srow) * K + kh + sc8);
            async_copy16((char*)&Bl[h][0] + (size_t)(wave * 64) * 16,
                         Bt + (size_t)(bn + srow) * K + kh + sc8);
            async_copy16((char*)&Bl[h][0] + (size_t)(512 + wave * 64) * 16,
                         Bt + (size_t)(bn + 128 + srow) * K + kh + sc8);
        }
        __syncthreads();
#pragma unroll
        for (int h = 0; h < 2; ++h) {
            bf16x8 af[4], bfr[4];
#pragma unroll
            for (int m = 0; m < 4; ++m)
                af[m] = *(const bf16x8*)(&Al[h][(wm + m * 16 + lrow) * 32 + lk8]);
#pragma unroll
            for (int n = 0; n < 4; ++n)
                bfr[n] = *(const bf16x8*)(&Bl[h][(wn + n * 16 + lrow) * 32 + lk8]);
#pragma unroll
            for (int m = 0; m < 4; ++m)
#pragma unroll
                for (int n = 0; n < 4; ++n)
                    acc[m][n] = __builtin_amdgcn_mfma_f32_16x16x32_bf16(
                        af[m], bfr[n], acc[m][n], 0, 0, 0);
        }
        __syncthreads();
    }
#pragma unroll
    for (int m = 0; m < 4; ++m) {
#pragma unroll
        for (int n = 0; n < 4; ++n) {
#pragma unroll
            for (int r = 0; r < 4; ++r) {
                int row = bm + wm + m * 16 + (lane >> 4) * 4 + r;
                int col = bn + wn + n * 16 + (lane & 15);
                if (row < M && col < N)
                    stf(&C[(size_t)row * N + col], acc[m][n][r]);
            }
        }
    }
}

// ---------------------------------------------------------------------------
// Depthwise conv + bias + silu, register-rolling over an 8-row L-tile
// (r14-proven best config).
// ---------------------------------------------------------------------------
__global__ __launch_bounds__(256) void conv_silu_kernel(
    const bf16* __restrict__ xz,
    const float* __restrict__ kx, const float* __restrict__ bx,
    const float* __restrict__ kz, const float* __restrict__ bz,
    bf16* __restrict__ xi, bf16* __restrict__ zo) {
    const int tid = threadIdx.x;
    const int d4 = tid * 4;                    // 0..1020
    const int blk = blockIdx.x;                // BL/8 blocks
    const int l0 = (blk * 8) & (SEQ_L - 1);
    const int b = (blk * 8) >> 12;             // /SEQ_L
    const unsigned short* base = (const unsigned short*)xz +
                                 ((size_t)b * SEQ_L) * (2 * D_INNERn);
    float4 wx[4], wz[4];
#pragma unroll
    for (int k = 0; k < 4; ++k) {
        wx[k] = *(const float4*)(kx + k * D_INNERn + d4);
        wz[k] = *(const float4*)(kz + k * D_INNERn + d4);
    }
    const float4 bxv = *(const float4*)(bx + d4);
    const float4 bzv = *(const float4*)(bz + d4);
    float4 vx[4], vz[4];
#pragma unroll
    for (int j = 0; j < 3; ++j) {
        int l = l0 - 1 + j;
        if (l >= 0) {
            const unsigned short* row = base + (size_t)l * (2 * D_INNERn);
            vx[j] = us4_to_f4(*(const ushort4*)(row + d4));
            vz[j] = us4_to_f4(*(const ushort4*)(row + D_INNERn + d4));
        } else {
            vx[j] = make_float4(0.f, 0.f, 0.f, 0.f);
            vz[j] = make_float4(0.f, 0.f, 0.f, 0.f);
        }
    }
    unsigned short* xout = (unsigned short*)xi;
    unsigned short* zout = (unsigned short*)zo;
#pragma unroll
    for (int j = 0; j < 8; ++j) {
        const int lread = l0 + 2 + j;
        if (lread < SEQ_L) {
            const unsigned short* row = base + (size_t)lread * (2 * D_INNERn);
            vx[3] = us4_to_f4(*(const ushort4*)(row + d4));
            vz[3] = us4_to_f4(*(const ushort4*)(row + D_INNERn + d4));
        } else {
            vx[3] = make_float4(0.f, 0.f, 0.f, 0.f);
            vz[3] = make_float4(0.f, 0.f, 0.f, 0.f);
        }
        float4 ax = bxv, az = bzv;
#pragma unroll
        for (int k = 0; k < 4; ++k) {
            ax.x += vx[k].x * wx[k].x; ax.y += vx[k].y * wx[k].y;
            ax.z += vx[k].z * wx[k].z; ax.w += vx[k].w * wx[k].w;
            az.x += vz[k].x * wz[k].x; az.y += vz[k].y * wz[k].y;
            az.z += vz[k].z * wz[k].z; az.w += vz[k].w * wz[k].w;
        }
        ushort4 ox, oz;
        ox.x = f2b(silu_f(ax.x)); ox.y = f2b(silu_f(ax.y));
        ox.z = f2b(silu_f(ax.z)); ox.w = f2b(silu_f(ax.w));
        oz.x = f2b(silu_f(az.x)); oz.y = f2b(silu_f(az.y));
        oz.z = f2b(silu_f(az.z)); oz.w = f2b(silu_f(az.w));
        const size_t obase = ((size_t)b * SEQ_L + l0 + j) * D_INNERn + d4;
        *(ushort4*)(xout + obase) = ox;
        *(ushort4*)(zout + obase) = oz;
        vx[0] = vx[1]; vx[1] = vx[2]; vx[2] = vx[3];
        vz[0] = vz[1]; vz[1] = vz[2]; vz[2] = vz[3];
    }
}

// ---------------------------------------------------------------------------
// MFMA SSD chunk: per (b,c,h) block, 4 waves.  dt=softplus fused; setprio.
// 37.7KB LDS (sWB aliases sCb) -> 4 blocks/CU (r18-proven).
// ---------------------------------------------------------------------------
__global__ __launch_bounds__(256) void ssd_chunk_mfma(
    const unsigned short* __restrict__ xdbl, const bf16* __restrict__ xi,
    const float* __restrict__ dt_bias, const float* __restrict__ A_log,
    const float* __restrict__ Dvec,
    unsigned short* __restrict__ y, unsigned short* __restrict__ S,
    float* __restrict__ acum_g, float* __restrict__ rchunk) {
    __shared__ __align__(16) unsigned short sBb[64 * 72];  // B[s][n]
    __shared__ __align__(16) unsigned short sCb[64 * 72];  // C[l][n]; reused as
                                                           // (w·B)^T[n][s] after MFMA1
    __shared__ __align__(16) unsigned short sXT[64 * 72];  // X^T[p][s]
    __shared__ __align__(16) unsigned short sGb[64 * 72];  // G[l][s]
    __shared__ float sdtp[64], sacum[64], sw[64];
    unsigned short* sWB = sCb;           // alias: sCb dead after MFMA1+barrier
    const int bid = blockIdx.x;          // ((b*64 + c)*16 + h)
    const int h = bid & 15;
    const int bc = bid >> 4;
    const int c = bc & (NCHUNK - 1);
    const int b = bc >> 6;
    const int tid = threadIdx.x;
    const int wave = tid >> 6, lane = tid & 63;
    const int lrow = lane & 15, lk8 = (lane >> 4) * 8;
    const int row0 = b * SEQ_L + c * CHUNKn;
    const float Ah = -expf(A_log[h]);
    const float Dh = Dvec[h];

    if (tid < 64) {  // fused dt = softplus(xdbl[..,h] + dt_bias[h])
        float v = b2f(xdbl[(size_t)(row0 + tid) * XDBL_N + h]) + dt_bias[h];
        sdtp[tid] = (v > 20.f) ? v : log1pf(expf(v));
    }
    const unsigned short* xius = (const unsigned short*)xi;
#pragma unroll
    for (int it = 0; it < 16; ++it) {
        int e = tid + it * 256;
        int s = e >> 6, n = e & 63;
        const unsigned short* xr = xdbl + (size_t)(row0 + s) * XDBL_N + N_HEADSn;
        sBb[s * 72 + n] = xr[n];
        sCb[s * 72 + n] = xr[D_STATEn + n];
        sXT[n * 72 + s] = xius[(size_t)(row0 + s) * D_INNERn + h * HEAD_DIMn + n];
    }
    __syncthreads();
    if (wave == 0) {
        float v = Ah * sdtp[lane];
#pragma unroll
        for (int o = 1; o < 64; o <<= 1) {
            float t = __shfl_up(v, o);
            if (lane >= o) v += t;
        }
        sacum[lane] = v;
        float last = __shfl(v, 63);
        sw[lane] = expf(last - v) * sdtp[lane];
        acum_g[(size_t)bid * 64 + lane] = v;
        if (lane == 63) rchunk[bid] = expf(v);
    }
    // MFMA1: Graw = C·B^T   (last read of sCb as C-operand)
    f32x4 acc1[4];
#pragma unroll
    for (int t = 0; t < 4; ++t) acc1[t] = (f32x4)(0.f);
    __builtin_amdgcn_s_setprio(1);
#pragma unroll
    for (int ks = 0; ks < 2; ++ks) {
        bf16x8 a = *(const bf16x8*)(&sCb[(wave * 16 + lrow) * 72 + ks * 32 + lk8]);
#pragma unroll
        for (int t = 0; t < 4; ++t) {
            bf16x8 bb = *(const bf16x8*)(&sBb[(t * 16 + lrow) * 72 + ks * 32 + lk8]);
            acc1[t] = __builtin_amdgcn_mfma_f32_16x16x32_bf16(a, bb, acc1[t], 0, 0, 0);
        }
    }
    __builtin_amdgcn_s_setprio(0);
    __syncthreads();   // after this barrier sCb storage is free -> sWB
#pragma unroll
    for (int t = 0; t < 4; ++t) {
#pragma unroll
        for (int r = 0; r < 4; ++r) {
            int l = wave * 16 + (lane >> 4) * 4 + r;
            int s = t * 16 + lrow;
            float val = 0.f;
            if (l >= s) val = acc1[t][r] * expf(sacum[l] - sacum[s]) * sdtp[s];
            sGb[l * 72 + s] = f2b(val);
        }
    }
#pragma unroll
    for (int it = 0; it < 16; ++it) {
        int e = tid + it * 256;
        int s = e >> 6, n = e & 63;
        sWB[n * 72 + s] = f2b(sw[s] * b2f(sBb[s * 72 + n]));
    }
    __syncthreads();
    f32x4 acc2[4], acc3[4];
#pragma unroll
    for (int t = 0; t < 4; ++t) { acc2[t] = (f32x4)(0.f); acc3[t] = (f32x4)(0.f); }
    __builtin_amdgcn_s_setprio(1);
#pragma unroll
    for (int ks = 0; ks < 2; ++ks) {
        bf16x8 a2 = *(const bf16x8*)(&sGb[(wave * 16 + lrow) * 72 + ks * 32 + lk8]);
        bf16x8 a3 = *(const bf16x8*)(&sXT[(wave * 16 + lrow) * 72 + ks * 32 + lk8]);
#pragma unroll
        for (int t = 0; t < 4; ++t) {
            bf16x8 b2v = *(const bf16x8*)(&sXT[(t * 16 + lrow) * 72 + ks * 32 + lk8]);
            bf16x8 b3v = *(const bf16x8*)(&sWB[(t * 16 + lrow) * 72 + ks * 32 + lk8]);
            acc2[t] = __builtin_amdgcn_mfma_f32_16x16x32_bf16(a2, b2v, acc2[t], 0, 0, 0);
            acc3[t] = __builtin_amdgcn_mfma_f32_16x16x32_bf16(a3, b3v, acc3[t], 0, 0, 0);
        }
    }
    __builtin_amdgcn_s_setprio(0);
#pragma unroll
    for (int t = 0; t < 4; ++t) {
#pragma unroll
        for (int r = 0; r < 4; ++r) {
            int rr = wave * 16 + (lane >> 4) * 4 + r;
            int cc = t * 16 + lrow;
            float xv = b2f(sXT[cc * 72 + rr]);
            y[(size_t)(row0 + rr) * D_INNERn + h * HEAD_DIMn + cc] =
                f2b(acc2[t][r] + Dh * xv);
            S[(size_t)bid * 4096 + rr * 64 + cc] = f2b(acc3[t][r]);
        }
    }
}

// ---------------------------------------------------------------------------
// Inter-chunk scan (bf16 S, f32 running state), software-prefetched:
// next chunk's load issues BEFORE the current store (breaks the
// load->store->load serialization; addresses provably distinct).
// ---------------------------------------------------------------------------
__global__ __launch_bounds__(256) void chunk_scan_kernel(
    unsigned short* __restrict__ S, const float* __restrict__ rchunk) {
    const int idx = blockIdx.x * 256 + threadIdx.x;  // BH * 2048
    const int pn2 = (idx & 2047) * 2;
    const int bh = idx >> 11;
    const int h = bh & 15;
    const int b = bh >> 4;
    float P0 = 0.f, P1 = 0.f;
    int bid = b * NCHUNK * N_HEADSn + h;
    size_t off = (size_t)bid * 4096 + pn2;
    unsigned int v = *(unsigned int*)(S + off);
    float rc = rchunk[bid];
    for (int c = 0; c < NCHUNK; ++c) {
        const size_t off_next = off + (size_t)N_HEADSn * 4096;
        unsigned int vn = 0;
        float rcn = 0.f;
        if (c + 1 < NCHUNK) {               // prefetch before the store
            vn = *(unsigned int*)(S + off_next);
            rcn = rchunk[bid + N_HEADSn];
        }
        float s0 = b2f((unsigned short)(v & 0xffff));
        float s1 = b2f((unsigned short)(v >> 16));
        *(unsigned int*)(S + off) =
            (unsigned int)f2b(P0) | ((unsigned int)f2b(P1) << 16);
        P0 = rc * P0 + s0;
        P1 = rc * P1 + s1;
        v = vn; rc = rcn; off = off_next; bid += N_HEADSn;
    }
}

// ---------------------------------------------------------------------------
// MFMA Y_off: y[l][p] += exp(acum[l]) * sum_n C[l][n] * P[p][n]  (all bf16)
// ---------------------------------------------------------------------------
__global__ __launch_bounds__(256) void yoff_mfma(
    const unsigned short* __restrict__ xdbl, const unsigned short* __restrict__ S,
    const float* __restrict__ acum_g, unsigned short* __restrict__ y) {
    __shared__ __align__(16) unsigned short sCb[64 * 72];
    __shared__ __align__(16) unsigned short sP[64 * 72];
    __shared__ float se[64];
    const int bid = blockIdx.x;
    const int h = bid & 15;
    const int bc = bid >> 4;
    const int c = bc & (NCHUNK - 1);
    const int b = bc >> 6;
    const int tid = threadIdx.x;
    const int wave = tid >> 6, lane = tid & 63;
    const int lrow = lane & 15, lk8 = (lane >> 4) * 8;
    const int row0 = b * SEQ_L + c * CHUNKn;
    if (tid < 64) se[tid] = expf(acum_g[(size_t)bid * 64 + tid]);
#pragma unroll
    for (int it = 0; it < 16; ++it) {
        int e = tid + it * 256;
        int r = e >> 6, n = e & 63;
        sCb[r * 72 + n] = xdbl[(size_t)(row0 + r) * XDBL_N + N_HEADSn + D_STATEn + n];
        sP[r * 72 + n] = S[(size_t)bid * 4096 + e];
    }
    __syncthreads();
    f32x4 acc[4];
#pragma unroll
    for (int t = 0; t < 4; ++t) acc[t] = (f32x4)(0.f);
    __builtin_amdgcn_s_setprio(1);
#pragma unroll
    for (int ks = 0; ks < 2; ++ks) {
        bf16x8 a = *(const bf16x8*)(&sCb[(wave * 16 + lrow) * 72 + ks * 32 + lk8]);
#pragma unroll
        for (int t = 0; t < 4; ++t) {
            bf16x8 bb = *(const bf16x8*)(&sP[(t * 16 + lrow) * 72 + ks * 32 + lk8]);
            acc[t] = __builtin_amdgcn_mfma_f32_16x16x32_bf16(a, bb, acc[t], 0, 0, 0);
        }
    }
    __builtin_amdgcn_s_setprio(0);
#pragma unroll
    for (int t = 0; t < 4; ++t) {
#pragma unroll
        for (int r = 0; r < 4; ++r) {
            int l = wave * 16 + (lane >> 4) * 4 + r;
            int p = t * 16 + lrow;
            size_t idx = (size_t)(row0 + l) * D_INNERn + h * HEAD_DIMn + p;
            y[idx] = f2b(b2f(y[idx]) + acc[t][r] * se[l]);
        }
    }
}

// ---------------------------------------------------------------------------
// y_bf = bf16( RMSNorm(y * silu(z)) * norm_weight )   (y input bf16)
// ---------------------------------------------------------------------------
__global__ __launch_bounds__(256) void gate_norm_kernel(
    const unsigned short* __restrict__ y, const bf16* __restrict__ zb,
    const float* __restrict__ nw, bf16* __restrict__ y_bf) {
    const int row = blockIdx.x;
    const int tid = threadIdx.x;
    const size_t base = (size_t)row * D_INNERn + tid * 4;
    ushort4 yu = *(const ushort4*)(y + base);
    ushort4 zu = *(const ushort4*)((const unsigned short*)zb + base);
    float v0 = b2f(yu.x) * silu_f(b2f(zu.x));
    float v1 = b2f(yu.y) * silu_f(b2f(zu.y));
    float v2 = b2f(yu.z) * silu_f(b2f(zu.z));
    float v3 = b2f(yu.w) * silu_f(b2f(zu.w));
    float ss = v0 * v0 + v1 * v1 + v2 * v2 + v3 * v3;
#pragma unroll
    for (int o = 32; o > 0; o >>= 1) ss += __shfl_xor(ss, o);
    __shared__ float sred[4];
    if ((tid & 63) == 0) sred[tid >> 6] = ss;
    __syncthreads();
    float total = sred[0] + sred[1] + sred[2] + sred[3];
    float scale = rsqrtf(total * (1.0f / D_INNERn) + 1e-5f);
    float4 wv = *(const float4*)(nw + tid * 4);
    ushort4 o4;
    o4.x = f2b(v0 * scale * wv.x);
    o4.y = f2b(v1 * scale * wv.y);
    o4.z = f2b(v2 * scale * wv.z);
    o4.w = f2b(v3 * scale * wv.w);
    *(ushort4*)((unsigned short*)y_bf + base) = o4;
}

// ---------------------------------------------------------------------------
extern "C" void kernel_launch(void* const* d_in, const int* in_sizes, int n_in,
                              void* d_out, int out_size, void* d_ws, size_t ws_size,
                              hipStream_t stream) {
    (void)in_sizes; (void)n_in; (void)out_size; (void)ws_size;
    const float* x       = (const float*)d_in[0];
    const float* W_in    = (const float*)d_in[1];
    const float* ckx     = (const float*)d_in[2];
    const float* cbx     = (const float*)d_in[3];
    const float* ckz     = (const float*)d_in[4];
    const float* cbz     = (const float*)d_in[5];
    const float* W_xdbl  = (const float*)d_in[6];
    const float* dt_bias = (const float*)d_in[7];
    const float* A_log   = (const float*)d_in[8];
    const float* Dvec    = (const float*)d_in[9];
    const float* nw      = (const float*)d_in[10];
    const float* W_out   = (const float*)d_in[11];
    float* out = (float*)d_out;   // f32 output (round-6 verified)
    char* w = (char*)d_ws;

    // Workspace layout (bytes), total 212,877,312 — proven size.
    bf16*  xz     = (bf16*)(w);               // [BL][2048] bf16 = 67,108,864
    unsigned short* y = (unsigned short*)(w); // alias: bf16 [BL][1024] (xz dead)
    bf16*  xi     = (bf16*)(w + 67108864);    // [BL][1024] bf16 = 33,554,432
    bf16*  zb     = (bf16*)(w + 100663296);   // [BL][1024] bf16 = 33,554,432
    char*  Sreg   = w + 134217728;            // 67,108,864 region, multi-use:
    unsigned short* S = (unsigned short*)Sreg;//   [4096][4096] bf16 = 33.5M (SSD)
    bf16*  x_bf   = (bf16*)Sreg;              //   prologue: [BL][512] bf16 = 16.8M
    bf16*  W_in_T = (bf16*)(Sreg + 16777216); //   prologue: [2048][512] bf16 = 2.1M
    bf16*  W_xd_T = (bf16*)(Sreg + 18874368); //   prologue: [144][1024] bf16 = 0.3M
    bf16*  y_bf   = (bf16*)Sreg;              //   epilogue: [BL][1024] bf16 = 33.5M
    bf16*  W_o_T  = (bf16*)(Sreg + 33554432); //   epilogue: [512][1024] bf16 = 1.0M
    unsigned short* xdbl = (unsigned short*)(w + 201326592);  // [BL][144] bf16 = 4.7M
    float* acum   = (float*)(w + 211812352);  // [4096][64] f32  =  1,048,576
    float* rchunk = (float*)(w + 212860928);  // [4096] f32      =     16,384

    // 0. prologue converts (into S region — dead until ssd_chunk)
    cvt_f32_bf16<<<BL * D_MODELn / 1024, 256, 0, stream>>>(x, x_bf);
    transpose_cvt<<<dim3(2048 / 32, 512 / 32), 256, 0, stream>>>(W_in, W_in_T, 512, 2048);
    transpose_cvt<<<dim3(5, 1024 / 32), 256, 0, stream>>>(W_xdbl, W_xd_T, 1024, 144);
    // 1. xz = x @ W_in  (MFMA wide 128x256, BK=64, XCD swizzle), store bf16
    gemm_mfma_wide<bf16><<<dim3(2048 / 256, BL / 128), 512, 0, stream>>>(
        x_bf, W_in_T, xz, BL, 2048, D_MODELn);
    // 2. conv + silu -> xi, zb (register-rolling 8-row tile, r14-proven)
    conv_silu_kernel<<<BL / 8, 256, 0, stream>>>(xz, ckx, cbx, ckz, cbz, xi, zb);
    // 3. x_dbl = xi @ W_xdbl  (MFMA 64x128 tile: 512 blocks, ~6 blk/CU cap)
    gemm_mfma_m64<bf16><<<dim3(2, BL / 64), 256, 0, stream>>>(
        xi, W_xd_T, (bf16*)xdbl, BL, XDBL_N, D_INNERn);
    // 4+5. SSD per-chunk (MFMA, dt fused, setprio, 37.7KB LDS): Y_diag + states
    ssd_chunk_mfma<<<B_SZn * NCHUNK * N_HEADSn, 256, 0, stream>>>(
        xdbl, xi, dt_bias, A_log, Dvec, y, S, acum, rchunk);
    // 6. inter-chunk scan (in place, bf16, software prefetch)
    chunk_scan_kernel<<<B_SZn * N_HEADSn * 2048 / 256, 256, 0, stream>>>(S, rchunk);
    // 7. Y_off accumulate (MFMA, bf16 RMW, setprio)
    yoff_mfma<<<B_SZn * NCHUNK * N_HEADSn, 256, 0, stream>>>(xdbl, S, acum, y);
    // 8. epilogue: W_out^T (S dead after yoff), gate+norm -> y_bf
    transpose_cvt<<<dim3(512 / 32, 1024 / 32), 256, 0, stream>>>(W_out, W_o_T, 1024, 512);
    gate_norm_kernel<<<BL, 256, 0, stream>>>(y, zb, nw, y_bf);
    // 9. out = y @ W_out  (MFMA 64x128 tile: 1024 blocks, 4/CU), store f32
    gemm_mfma_m64<float><<<dim3(512 / 128, BL / 64), 256, 0, stream>>>(
        y_bf, W_o_T, out, BL, D_MODELn, D_INNERn);
}

// Round 20
// 222.952 us; speedup vs baseline: 1.1005x; 1.0367x over previous
//
#include <hip/hip_runtime.h>
#include <hip/hip_bf16.h>
#include <cstdint>

#define B_SZn 4
#define SEQ_L 4096
#define D_MODELn 512
#define D_INNERn 1024
#define N_HEADSn 16
#define HEAD_DIMn 64
#define D_STATEn 64
#define CHUNKn 64
#define NCHUNK (SEQ_L / CHUNKn)          // 64
#define BL (B_SZn * SEQ_L)               // 16384
#define XDBL_N (N_HEADSn + 2 * D_STATEn) // 144

typedef __hip_bfloat16 bf16;
typedef __bf16 bf16x8 __attribute__((ext_vector_type(8)));
typedef float f32x4 __attribute__((ext_vector_type(4)));

__device__ __forceinline__ float silu_f(float v) {
    return v / (1.0f + expf(-v));
}
__device__ __forceinline__ float b2f(unsigned short u) {
    return __uint_as_float((unsigned)u << 16);
}
__device__ __forceinline__ unsigned short f2b(float f) {
    bf16 h = __float2bfloat16(f);
    return *(unsigned short*)&h;
}
__device__ __forceinline__ void stf(float* p, float v) { *p = v; }
__device__ __forceinline__ void stf(bf16* p, float v) { *p = __float2bfloat16(v); }

__device__ __forceinline__ float4 us4_to_f4(ushort4 u) {
    float4 f;
    f.x = b2f(u.x); f.y = b2f(u.y); f.z = b2f(u.z); f.w = b2f(u.w);
    return f;
}

// async global->LDS 16B copy (m97/m193-proven pattern).
__device__ __forceinline__ void async_copy16(void* lds, const void* g) {
    __builtin_amdgcn_global_load_lds(
        (const __attribute__((address_space(1))) unsigned int*)g,
        (__attribute__((address_space(3))) unsigned int*)lds, 16, 0, 0);
}

// ---------------------------------------------------------------------------
// Fused prologue (1 launch instead of 4):
//   blocks [0,8192):        x f32 -> x_bf
//   blocks [8192,9216):     W_in^T   (512x2048 -> 2048x512 bf16)
//   blocks [9216,9376):     W_xdbl^T (1024x144 -> 144x1024 bf16)
//   blocks [9376,9888):     W_out^T  (1024x512 -> 512x1024 bf16)
// W_o_T lives at Sreg+33.5MB: outside S's [0,33.5MB) -> survives to GEMM4.
// ---------------------------------------------------------------------------
__global__ __launch_bounds__(256) void prologue_kernel(
    const float* __restrict__ x, const float* __restrict__ W_in,
    const float* __restrict__ W_xdbl, const float* __restrict__ W_out,
    bf16* __restrict__ x_bf, bf16* __restrict__ W_in_T,
    bf16* __restrict__ W_xd_T, bf16* __restrict__ W_o_T) {
    __shared__ float tle[32][33];
    int blk = blockIdx.x;
    if (blk < 8192) {  // x convert: 8192 blocks x 1024 f32
        const int idx = blk * 256 + threadIdx.x;
        float4 v = *(const float4*)(x + (size_t)idx * 4);
        ushort4 o;
        o.x = f2b(v.x); o.y = f2b(v.y); o.z = f2b(v.z); o.w = f2b(v.w);
        *(ushort4*)((unsigned short*)x_bf + (size_t)idx * 4) = o;
        return;
    }
    blk -= 8192;
    const float* src; bf16* dst; int R, C, bx, by;
    if (blk < 1024)      { src = W_in;   dst = W_in_T; R = 512;  C = 2048;
                           bx = blk & 63;        by = blk >> 6; }
    else if (blk < 1184) { int t = blk - 1024; src = W_xdbl; dst = W_xd_T;
                           R = 1024; C = 144;  bx = t % 5;  by = t / 5; }
    else                 { int t = blk - 1184; src = W_out;  dst = W_o_T;
                           R = 1024; C = 512;  bx = t & 15; by = t >> 4; }
    const int bc = bx * 32, br = by * 32;
    const int tx = threadIdx.x & 31, ty = threadIdx.x >> 5;
#pragma unroll
    for (int i = ty; i < 32; i += 8) {
        int r = br + i, c = bc + tx;
        tle[i][tx] = (r < R && c < C) ? src[(size_t)r * C + c] : 0.f;
    }
    __syncthreads();
#pragma unroll
    for (int i = ty; i < 32; i += 8) {
        int c = bc + i, r = br + tx;
        if (c < C && r < R) dst[(size_t)c * R + r] = __float2bfloat16(tle[tx][i]);
    }
}

// ---------------------------------------------------------------------------
// Small-M bf16 MFMA GEMM for tall-skinny shapes (GEMM2/GEMM3, r19-proven):
// 64x128 tile, BK=64 half-split, single-buffered global_load_lds, XCD
// swizzle.  4 waves (2Mx2N), 24KB LDS -> ~6 blocks/CU.
// ---------------------------------------------------------------------------
template <typename TO>
__global__ __launch_bounds__(256) void gemm_mfma_m64(
    const bf16* __restrict__ A, const bf16* __restrict__ Bt,
    TO* __restrict__ C, int M, int N, int K) {
    __shared__ __align__(16) unsigned short Al[2][64 * 32];
    __shared__ __align__(16) unsigned short Bl[2][128 * 32];
    const int tid = threadIdx.x;
    const int wave = tid >> 6, lane = tid & 63;
    const int wm = (wave >> 1) * 32, wn = (wave & 1) * 64;
    int lin = blockIdx.y * gridDim.x + blockIdx.x;
    const int nwg = gridDim.x * gridDim.y;
    if ((nwg & 7) == 0) lin = (lin & 7) * (nwg >> 3) + (lin >> 3);
    const int bm = (lin / gridDim.x) * 64, bn = (lin % gridDim.x) * 128;
    f32x4 acc[2][4];
#pragma unroll
    for (int m = 0; m < 2; ++m)
#pragma unroll
        for (int n = 0; n < 4; ++n) acc[m][n] = (f32x4)(0.f);

    const int lrow = lane & 15, lk8 = (lane >> 4) * 8;
    const int srow = tid >> 2, sc8 = (tid & 3) * 8;
    for (int k0 = 0; k0 < K; k0 += 64) {
#pragma unroll
        for (int h = 0; h < 2; ++h) {
            const int kh = k0 + h * 32;
            async_copy16((char*)&Al[h][0] + (size_t)(wave * 64) * 16,
                         A + (size_t)(bm + srow) * K + kh + sc8);
            async_copy16((char*)&Bl[h][0] + (size_t)(wave * 64) * 16,
                         Bt + (size_t)(bn + srow) * K + kh + sc8);
            async_copy16((char*)&Bl[h][0] + (size_t)(256 + wave * 64) * 16,
                         Bt + (size_t)(bn + 64 + srow) * K + kh + sc8);
        }
        __syncthreads();
#pragma unroll
        for (int h = 0; h < 2; ++h) {
            bf16x8 af[2], bfr[4];
#pragma unroll
            for (int m = 0; m < 2; ++m)
                af[m] = *(const bf16x8*)(&Al[h][(wm + m * 16 + lrow) * 32 + lk8]);
#pragma unroll
            for (int n = 0; n < 4; ++n)
                bfr[n] = *(const bf16x8*)(&Bl[h][(wn + n * 16 + lrow) * 32 + lk8]);
#pragma unroll
            for (int m = 0; m < 2; ++m)
#pragma unroll
                for (int n = 0; n < 4; ++n)
                    acc[m][n] = __builtin_amdgcn_mfma_f32_16x16x32_bf16(
                        af[m], bfr[n], acc[m][n], 0, 0, 0);
        }
        __syncthreads();
    }
#pragma unroll
    for (int m = 0; m < 2; ++m) {
#pragma unroll
        for (int n = 0; n < 4; ++n) {
#pragma unroll
            for (int r = 0; r < 4; ++r) {
                int row = bm + wm + m * 16 + (lane >> 4) * 4 + r;
                int col = bn + wn + n * 16 + (lane & 15);
                if (row < M && col < N)
                    stf(&C[(size_t)row * N + col], acc[m][n][r]);
            }
        }
    }
}

// ---------------------------------------------------------------------------
// Wide-N variant (r14-proven for GEMM1): 128x256 tile, 8 waves (2Mx4N),
// 512 threads, BK=64 half-split, 48KB LDS (3 blocks/CU).
// ---------------------------------------------------------------------------
template <typename TO>
__global__ __launch_bounds__(512) void gemm_mfma_wide(
    const bf16* __restrict__ A, const bf16* __restrict__ Bt,
    TO* __restrict__ C, int M, int N, int K) {
    __shared__ __align__(16) unsigned short Al[2][128 * 32];
    __shared__ __align__(16) unsigned short Bl[2][256 * 32];
    const int tid = threadIdx.x;
    const int wave = tid >> 6, lane = tid & 63;
    const int wm = (wave >> 2) * 64, wn = (wave & 3) * 64;
    int lin = blockIdx.y * gridDim.x + blockIdx.x;
    const int nwg = gridDim.x * gridDim.y;
    if ((nwg & 7) == 0) lin = (lin & 7) * (nwg >> 3) + (lin >> 3);
    const int bm = (lin / gridDim.x) * 128, bn = (lin % gridDim.x) * 256;
    f32x4 acc[4][4];
#pragma unroll
    for (int m = 0; m < 4; ++m)
#pragma unroll
        for (int n = 0; n < 4; ++n) acc[m][n] = (f32x4)(0.f);

    const int lrow = lane & 15, lk8 = (lane >> 4) * 8;
    const int srow = tid >> 2, sc8 = (tid & 3) * 8;  // 512 thr: A 1 seg, B 2 segs
    for (int k0 = 0; k0 < K; k0 += 64) {
#pragma unroll
        for (int h = 0; h < 2; ++h) {
            const int kh = k0 + h * 32;
            async_copy16((char*)&Al[h][0] + (size_t)(wave * 64) * 16,
                         A + (size_t)(bm + srow) * K + kh + sc8);
            async_copy16((char*)&Bl[h][0] + (size_t)(wave * 64) * 16,
                         Bt + (size_t)(bn + srow) * K + kh + sc8);
            async_copy16((char*)&Bl[h][0] + (size_t)(512 + wave * 64) * 16,
                         Bt + (size_t)(bn + 128 + srow) * K + kh + sc8);
        }
        __syncthreads();
#pragma unroll
        for (int h = 0; h < 2; ++h) {
            bf16x8 af[4], bfr[4];
#pragma unroll
            for (int m = 0; m < 4; ++m)
                af[m] = *(const bf16x8*)(&Al[h][(wm + m * 16 + lrow) * 32 + lk8]);
#pragma unroll
            for (int n = 0; n < 4; ++n)
                bfr[n] = *(const bf16x8*)(&Bl[h][(wn + n * 16 + lrow) * 32 + lk8]);
#pragma unroll
            for (int m = 0; m < 4; ++m)
#pragma unroll
                for (int n = 0; n < 4; ++n)
                    acc[m][n] = __builtin_amdgcn_mfma_f32_16x16x32_bf16(
                        af[m], bfr[n], acc[m][n], 0, 0, 0);
        }
        __syncthreads();
    }
#pragma unroll
    for (int m = 0; m < 4; ++m) {
#pragma unroll
        for (int n = 0; n < 4; ++n) {
#pragma unroll
            for (int r = 0; r < 4; ++r) {
                int row = bm + wm + m * 16 + (lane >> 4) * 4 + r;
                int col = bn + wn + n * 16 + (lane & 15);
                if (row < M && col < N)
                    stf(&C[(size_t)row * N + col], acc[m][n][r]);
            }
        }
    }
}

// ---------------------------------------------------------------------------
// Depthwise conv + bias + silu, register-rolling over an 8-row L-tile
// (r14-proven best config).
// ---------------------------------------------------------------------------
__global__ __launch_bounds__(256) void conv_silu_kernel(
    const bf16* __restrict__ xz,
    const float* __restrict__ kx, const float* __restrict__ bx,
    const float* __restrict__ kz, const float* __restrict__ bz,
    bf16* __restrict__ xi, bf16* __restrict__ zo) {
    const int tid = threadIdx.x;
    const int d4 = tid * 4;                    // 0..1020
    const int blk = blockIdx.x;                // BL/8 blocks
    const int l0 = (blk * 8) & (SEQ_L - 1);
    const int b = (blk * 8) >> 12;             // /SEQ_L
    const unsigned short* base = (const unsigned short*)xz +
                                 ((size_t)b * SEQ_L) * (2 * D_INNERn);
    float4 wx[4], wz[4];
#pragma unroll
    for (int k = 0; k < 4; ++k) {
        wx[k] = *(const float4*)(kx + k * D_INNERn + d4);
        wz[k] = *(const float4*)(kz + k * D_INNERn + d4);
    }
    const float4 bxv = *(const float4*)(bx + d4);
    const float4 bzv = *(const float4*)(bz + d4);
    float4 vx[4], vz[4];
#pragma unroll
    for (int j = 0; j < 3; ++j) {
        int l = l0 - 1 + j;
        if (l >= 0) {
            const unsigned short* row = base + (size_t)l * (2 * D_INNERn);
            vx[j] = us4_to_f4(*(const ushort4*)(row + d4));
            vz[j] = us4_to_f4(*(const ushort4*)(row + D_INNERn + d4));
        } else {
            vx[j] = make_float4(0.f, 0.f, 0.f, 0.f);
            vz[j] = make_float4(0.f, 0.f, 0.f, 0.f);
        }
    }
    unsigned short* xout = (unsigned short*)xi;
    unsigned short* zout = (unsigned short*)zo;
#pragma unroll
    for (int j = 0; j < 8; ++j) {
        const int lread = l0 + 2 + j;
        if (lread < SEQ_L) {
            const unsigned short* row = base + (size_t)lread * (2 * D_INNERn);
            vx[3] = us4_to_f4(*(const ushort4*)(row + d4));
            vz[3] = us4_to_f4(*(const ushort4*)(row + D_INNERn + d4));
        } else {
            vx[3] = make_float4(0.f, 0.f, 0.f, 0.f);
            vz[3] = make_float4(0.f, 0.f, 0.f, 0.f);
        }
        float4 ax = bxv, az = bzv;
#pragma unroll
        for (int k = 0; k < 4; ++k) {
            ax.x += vx[k].x * wx[k].x; ax.y += vx[k].y * wx[k].y;
            ax.z += vx[k].z * wx[k].z; ax.w += vx[k].w * wx[k].w;
            az.x += vz[k].x * wz[k].x; az.y += vz[k].y * wz[k].y;
            az.z += vz[k].z * wz[k].z; az.w += vz[k].w * wz[k].w;
        }
        ushort4 ox, oz;
        ox.x = f2b(silu_f(ax.x)); ox.y = f2b(silu_f(ax.y));
        ox.z = f2b(silu_f(ax.z)); ox.w = f2b(silu_f(ax.w));
        oz.x = f2b(silu_f(az.x)); oz.y = f2b(silu_f(az.y));
        oz.z = f2b(silu_f(az.z)); oz.w = f2b(silu_f(az.w));
        const size_t obase = ((size_t)b * SEQ_L + l0 + j) * D_INNERn + d4;
        *(ushort4*)(xout + obase) = ox;
        *(ushort4*)(zout + obase) = oz;
        vx[0] = vx[1]; vx[1] = vx[2]; vx[2] = vx[3];
        vz[0] = vz[1]; vz[1] = vz[2]; vz[2] = vz[3];
    }
}

// ---------------------------------------------------------------------------
// MFMA SSD chunk: per (b,c,h) block, 4 waves.  dt=softplus fused; setprio.
// 37.7KB LDS (sWB aliases sCb) -> 4 blocks/CU (r18-proven).
// ---------------------------------------------------------------------------
__global__ __launch_bounds__(256) void ssd_chunk_mfma(
    const unsigned short* __restrict__ xdbl, const bf16* __restrict__ xi,
    const float* __restrict__ dt_bias, const float* __restrict__ A_log,
    const float* __restrict__ Dvec,
    unsigned short* __restrict__ y, unsigned short* __restrict__ S,
    float* __restrict__ acum_g, float* __restrict__ rchunk) {
    __shared__ __align__(16) unsigned short sBb[64 * 72];  // B[s][n]
    __shared__ __align__(16) unsigned short sCb[64 * 72];  // C[l][n]; reused as
                                                           // (w·B)^T[n][s] after MFMA1
    __shared__ __align__(16) unsigned short sXT[64 * 72];  // X^T[p][s]
    __shared__ __align__(16) unsigned short sGb[64 * 72];  // G[l][s]
    __shared__ float sdtp[64], sacum[64], sw[64];
    unsigned short* sWB = sCb;           // alias: sCb dead after MFMA1+barrier
    const int bid = blockIdx.x;          // ((b*64 + c)*16 + h)
    const int h = bid & 15;
    const int bc = bid >> 4;
    const int c = bc & (NCHUNK - 1);
    const int b = bc >> 6;
    const int tid = threadIdx.x;
    const int wave = tid >> 6, lane = tid & 63;
    const int lrow = lane & 15, lk8 = (lane >> 4) * 8;
    const int row0 = b * SEQ_L + c * CHUNKn;
    const float Ah = -expf(A_log[h]);
    const float Dh = Dvec[h];

    if (tid < 64) {  // fused dt = softplus(xdbl[..,h] + dt_bias[h])
        float v = b2f(xdbl[(size_t)(row0 + tid) * XDBL_N + h]) + dt_bias[h];
        sdtp[tid] = (v > 20.f) ? v : log1pf(expf(v));
    }
    const unsigned short* xius = (const unsigned short*)xi;
#pragma unroll
    for (int it = 0; it < 16; ++it) {
        int e = tid + it * 256;
        int s = e >> 6, n = e & 63;
        const unsigned short* xr = xdbl + (size_t)(row0 + s) * XDBL_N + N_HEADSn;
        sBb[s * 72 + n] = xr[n];
        sCb[s * 72 + n] = xr[D_STATEn + n];
        sXT[n * 72 + s] = xius[(size_t)(row0 + s) * D_INNERn + h * HEAD_DIMn + n];
    }
    __syncthreads();
    if (wave == 0) {
        float v = Ah * sdtp[lane];
#pragma unroll
        for (int o = 1; o < 64; o <<= 1) {
            float t = __shfl_up(v, o);
            if (lane >= o) v += t;
        }
        sacum[lane] = v;
        float last = __shfl(v, 63);
        sw[lane] = expf(last - v) * sdtp[lane];
        acum_g[(size_t)bid * 64 + lane] = v;
        if (lane == 63) rchunk[bid] = expf(v);
    }
    // MFMA1: Graw = C·B^T   (last read of sCb as C-operand)
    f32x4 acc1[4];
#pragma unroll
    for (int t = 0; t < 4; ++t) acc1[t] = (f32x4)(0.f);
    __builtin_amdgcn_s_setprio(1);
#pragma unroll
    for (int ks = 0; ks < 2; ++ks) {
        bf16x8 a = *(const bf16x8*)(&sCb[(wave * 16 + lrow) * 72 + ks * 32 + lk8]);
#pragma unroll
        for (int t = 0; t < 4; ++t) {
            bf16x8 bb = *(const bf16x8*)(&sBb[(t * 16 + lrow) * 72 + ks * 32 + lk8]);
            acc1[t] = __builtin_amdgcn_mfma_f32_16x16x32_bf16(a, bb, acc1[t], 0, 0, 0);
        }
    }
    __builtin_amdgcn_s_setprio(0);
    __syncthreads();   // after this barrier sCb storage is free -> sWB
#pragma unroll
    for (int t = 0; t < 4; ++t) {
#pragma unroll
        for (int r = 0; r < 4; ++r) {
            int l = wave * 16 + (lane >> 4) * 4 + r;
            int s = t * 16 + lrow;
            float val = 0.f;
            if (l >= s) val = acc1[t][r] * expf(sacum[l] - sacum[s]) * sdtp[s];
            sGb[l * 72 + s] = f2b(val);
        }
    }
#pragma unroll
    for (int it = 0; it < 16; ++it) {
        int e = tid + it * 256;
        int s = e >> 6, n = e & 63;
        sWB[n * 72 + s] = f2b(sw[s] * b2f(sBb[s * 72 + n]));
    }
    __syncthreads();
    f32x4 acc2[4], acc3[4];
#pragma unroll
    for (int t = 0; t < 4; ++t) { acc2[t] = (f32x4)(0.f); acc3[t] = (f32x4)(0.f); }
    __builtin_amdgcn_s_setprio(1);
#pragma unroll
    for (int ks = 0; ks < 2; ++ks) {
        bf16x8 a2 = *(const bf16x8*)(&sGb[(wave * 16 + lrow) * 72 + ks * 32 + lk8]);
        bf16x8 a3 = *(const bf16x8*)(&sXT[(wave * 16 + lrow) * 72 + ks * 32 + lk8]);
#pragma unroll
        for (int t = 0; t < 4; ++t) {
            bf16x8 b2v = *(const bf16x8*)(&sXT[(t * 16 + lrow) * 72 + ks * 32 + lk8]);
            bf16x8 b3v = *(const bf16x8*)(&sWB[(t * 16 + lrow) * 72 + ks * 32 + lk8]);
            acc2[t] = __builtin_amdgcn_mfma_f32_16x16x32_bf16(a2, b2v, acc2[t], 0, 0, 0);
            acc3[t] = __builtin_amdgcn_mfma_f32_16x16x32_bf16(a3, b3v, acc3[t], 0, 0, 0);
        }
    }
    __builtin_amdgcn_s_setprio(0);
#pragma unroll
    for (int t = 0; t < 4; ++t) {
#pragma unroll
        for (int r = 0; r < 4; ++r) {
            int rr = wave * 16 + (lane >> 4) * 4 + r;
            int cc = t * 16 + lrow;
            float xv = b2f(sXT[cc * 72 + rr]);
            y[(size_t)(row0 + rr) * D_INNERn + h * HEAD_DIMn + cc] =
                f2b(acc2[t][r] + Dh * xv);
            S[(size_t)bid * 4096 + rr * 64 + cc] = f2b(acc3[t][r]);
        }
    }
}

// ---------------------------------------------------------------------------
// Inter-chunk scan (bf16 S, f32 running state), software-prefetched
// (r19-proven).
// ---------------------------------------------------------------------------
__global__ __launch_bounds__(256) void chunk_scan_kernel(
    unsigned short* __restrict__ S, const float* __restrict__ rchunk) {
    const int idx = blockIdx.x * 256 + threadIdx.x;  // BH * 2048
    const int pn2 = (idx & 2047) * 2;
    const int bh = idx >> 11;
    const int h = bh & 15;
    const int b = bh >> 4;
    float P0 = 0.f, P1 = 0.f;
    int bid = b * NCHUNK * N_HEADSn + h;
    size_t off = (size_t)bid * 4096 + pn2;
    unsigned int v = *(unsigned int*)(S + off);
    float rc = rchunk[bid];
    for (int c = 0; c < NCHUNK; ++c) {
        const size_t off_next = off + (size_t)N_HEADSn * 4096;
        unsigned int vn = 0;
        float rcn = 0.f;
        if (c + 1 < NCHUNK) {               // prefetch before the store
            vn = *(unsigned int*)(S + off_next);
            rcn = rchunk[bid + N_HEADSn];
        }
        float s0 = b2f((unsigned short)(v & 0xffff));
        float s1 = b2f((unsigned short)(v >> 16));
        *(unsigned int*)(S + off) =
            (unsigned int)f2b(P0) | ((unsigned int)f2b(P1) << 16);
        P0 = rc * P0 + s0;
        P1 = rc * P1 + s1;
        v = vn; rc = rcn; off = off_next; bid += N_HEADSn;
    }
}

// ---------------------------------------------------------------------------
// MFMA Y_off: y[l][p] += exp(acum[l]) * sum_n C[l][n] * P[p][n]  (all bf16)
// ---------------------------------------------------------------------------
__global__ __launch_bounds__(256) void yoff_mfma(
    const unsigned short* __restrict__ xdbl, const unsigned short* __restrict__ S,
    const float* __restrict__ acum_g, unsigned short* __restrict__ y) {
    __shared__ __align__(16) unsigned short sCb[64 * 72];
    __shared__ __align__(16) unsigned short sP[64 * 72];
    __shared__ float se[64];
    const int bid = blockIdx.x;
    const int h = bid & 15;
    const int bc = bid >> 4;
    const int c = bc & (NCHUNK - 1);
    const int b = bc >> 6;
    const int tid = threadIdx.x;
    const int wave = tid >> 6, lane = tid & 63;
    const int lrow = lane & 15, lk8 = (lane >> 4) * 8;
    const int row0 = b * SEQ_L + c * CHUNKn;
    if (tid < 64) se[tid] = expf(acum_g[(size_t)bid * 64 + tid]);
#pragma unroll
    for (int it = 0; it < 16; ++it) {
        int e = tid + it * 256;
        int r = e >> 6, n = e & 63;
        sCb[r * 72 + n] = xdbl[(size_t)(row0 + r) * XDBL_N + N_HEADSn + D_STATEn + n];
        sP[r * 72 + n] = S[(size_t)bid * 4096 + e];
    }
    __syncthreads();
    f32x4 acc[4];
#pragma unroll
    for (int t = 0; t < 4; ++t) acc[t] = (f32x4)(0.f);
    __builtin_amdgcn_s_setprio(1);
#pragma unroll
    for (int ks = 0; ks < 2; ++ks) {
        bf16x8 a = *(const bf16x8*)(&sCb[(wave * 16 + lrow) * 72 + ks * 32 + lk8]);
#pragma unroll
        for (int t = 0; t < 4; ++t) {
            bf16x8 bb = *(const bf16x8*)(&sP[(t * 16 + lrow) * 72 + ks * 32 + lk8]);
            acc[t] = __builtin_amdgcn_mfma_f32_16x16x32_bf16(a, bb, acc[t], 0, 0, 0);
        }
    }
    __builtin_amdgcn_s_setprio(0);
#pragma unroll
    for (int t = 0; t < 4; ++t) {
#pragma unroll
        for (int r = 0; r < 4; ++r) {
            int l = wave * 16 + (lane >> 4) * 4 + r;
            int p = t * 16 + lrow;
            size_t idx = (size_t)(row0 + l) * D_INNERn + h * HEAD_DIMn + p;
            y[idx] = f2b(b2f(y[idx]) + acc[t][r] * se[l]);
        }
    }
}

// ---------------------------------------------------------------------------
// y_bf = bf16( RMSNorm(y * silu(z)) * norm_weight )   (y input bf16)
// ---------------------------------------------------------------------------
__global__ __launch_bounds__(256) void gate_norm_kernel(
    const unsigned short* __restrict__ y, const bf16* __restrict__ zb,
    const float* __restrict__ nw, bf16* __restrict__ y_bf) {
    const int row = blockIdx.x;
    const int tid = threadIdx.x;
    const size_t base = (size_t)row * D_INNERn + tid * 4;
    ushort4 yu = *(const ushort4*)(y + base);
    ushort4 zu = *(const ushort4*)((const unsigned short*)zb + base);
    float v0 = b2f(yu.x) * silu_f(b2f(zu.x));
    float v1 = b2f(yu.y) * silu_f(b2f(zu.y));
    float v2 = b2f(yu.z) * silu_f(b2f(zu.z));
    float v3 = b2f(yu.w) * silu_f(b2f(zu.w));
    float ss = v0 * v0 + v1 * v1 + v2 * v2 + v3 * v3;
#pragma unroll
    for (int o = 32; o > 0; o >>= 1) ss += __shfl_xor(ss, o);
    __shared__ float sred[4];
    if ((tid & 63) == 0) sred[tid >> 6] = ss;
    __syncthreads();
    float total = sred[0] + sred[1] + sred[2] + sred[3];
    float scale = rsqrtf(total * (1.0f / D_INNERn) + 1e-5f);
    float4 wv = *(const float4*)(nw + tid * 4);
    ushort4 o4;
    o4.x = f2b(v0 * scale * wv.x);
    o4.y = f2b(v1 * scale * wv.y);
    o4.z = f2b(v2 * scale * wv.z);
    o4.w = f2b(v3 * scale * wv.w);
    *(ushort4*)((unsigned short*)y_bf + base) = o4;
}

// ---------------------------------------------------------------------------
extern "C" void kernel_launch(void* const* d_in, const int* in_sizes, int n_in,
                              void* d_out, int out_size, void* d_ws, size_t ws_size,
                              hipStream_t stream) {
    (void)in_sizes; (void)n_in; (void)out_size; (void)ws_size;
    const float* x       = (const float*)d_in[0];
    const float* W_in    = (const float*)d_in[1];
    const float* ckx     = (const float*)d_in[2];
    const float* cbx     = (const float*)d_in[3];
    const float* ckz     = (const float*)d_in[4];
    const float* cbz     = (const float*)d_in[5];
    const float* W_xdbl  = (const float*)d_in[6];
    const float* dt_bias = (const float*)d_in[7];
    const float* A_log   = (const float*)d_in[8];
    const float* Dvec    = (const float*)d_in[9];
    const float* nw      = (const float*)d_in[10];
    const float* W_out   = (const float*)d_in[11];
    float* out = (float*)d_out;   // f32 output (round-6 verified)
    char* w = (char*)d_ws;

    // Workspace layout (bytes), total 212,877,312 — proven size.
    bf16*  xz     = (bf16*)(w);               // [BL][2048] bf16 = 67,108,864
    unsigned short* y = (unsigned short*)(w); // alias: bf16 [BL][1024] (xz dead)
    bf16*  xi     = (bf16*)(w + 67108864);    // [BL][1024] bf16 = 33,554,432
    bf16*  zb     = (bf16*)(w + 100663296);   // [BL][1024] bf16 = 33,554,432
    char*  Sreg   = w + 134217728;            // 67,108,864 region, multi-use:
    unsigned short* S = (unsigned short*)Sreg;//   [4096][4096] bf16 = 33.5M (SSD)
    bf16*  x_bf   = (bf16*)Sreg;              //   prologue: [BL][512] bf16 = 16.8M
    bf16*  W_in_T = (bf16*)(Sreg + 16777216); //   prologue: [2048][512] bf16 = 2.1M
    bf16*  W_xd_T = (bf16*)(Sreg + 18874368); //   prologue: [144][1024] bf16 = 0.3M
    bf16*  y_bf   = (bf16*)Sreg;              //   epilogue: [BL][1024] bf16 = 33.5M
    bf16*  W_o_T  = (bf16*)(Sreg + 33554432); //   [512][1024] bf16 = 1.0M
                                              //   (outside S: survives to GEMM4)
    unsigned short* xdbl = (unsigned short*)(w + 201326592);  // [BL][144] bf16 = 4.7M
    float* acum   = (float*)(w + 211812352);  // [4096][64] f32  =  1,048,576
    float* rchunk = (float*)(w + 212860928);  // [4096] f32      =     16,384

    // 0. fused prologue (1 launch): x cvt + all three weight transposes
    prologue_kernel<<<9888, 256, 0, stream>>>(
        x, W_in, W_xdbl, W_out, x_bf, W_in_T, W_xd_T, W_o_T);
    // 1. xz = x @ W_in  (MFMA wide 128x256, BK=64, XCD swizzle), store bf16
    gemm_mfma_wide<bf16><<<dim3(2048 / 256, BL / 128), 512, 0, stream>>>(
        x_bf, W_in_T, xz, BL, 2048, D_MODELn);
    // 2. conv + silu -> xi, zb (register-rolling 8-row tile, r14-proven)
    conv_silu_kernel<<<BL / 8, 256, 0, stream>>>(xz, ckx, cbx, ckz, cbz, xi, zb);
    // 3. x_dbl = xi @ W_xdbl  (MFMA 64x128 tile: 512 blocks)
    gemm_mfma_m64<bf16><<<dim3(2, BL / 64), 256, 0, stream>>>(
        xi, W_xd_T, (bf16*)xdbl, BL, XDBL_N, D_INNERn);
    // 4+5. SSD per-chunk (MFMA, dt fused, setprio, 37.7KB LDS): Y_diag + states
    ssd_chunk_mfma<<<B_SZn * NCHUNK * N_HEADSn, 256, 0, stream>>>(
        xdbl, xi, dt_bias, A_log, Dvec, y, S, acum, rchunk);
    // 6. inter-chunk scan (in place, bf16, software prefetch)
    chunk_scan_kernel<<<B_SZn * N_HEADSn * 2048 / 256, 256, 0, stream>>>(S, rchunk);
    // 7. Y_off accumulate (MFMA, bf16 RMW, setprio)
    yoff_mfma<<<B_SZn * NCHUNK * N_HEADSn, 256, 0, stream>>>(xdbl, S, acum, y);
    // 8. gating + RMS norm -> y_bf
    gate_norm_kernel<<<BL, 256, 0, stream>>>(y, zb, nw, y_bf);
    // 9. out = y @ W_out  (MFMA 64x128 tile: 1024 blocks, 4/CU), store f32
    gemm_mfma_m64<float><<<dim3(512 / 128, BL / 64), 256, 0, stream>>>(
        y_bf, W_o_T, out, BL, D_MODELn, D_INNERn);
}